// Round 1
// 5444.130 us; speedup vs baseline: 1.1386x; 1.1386x over previous
//
#include <hip/hip_runtime.h>
#include <math.h>

typedef __attribute__((ext_vector_type(4))) float floatx4;
typedef __attribute__((ext_vector_type(8))) short bf16x8;
typedef unsigned short u16;

#define NTOK 4050
#define KW 23
#define NROW 1035
#define SZ_ALL 3110400.0f
#define LAMF 0.01f
#define LD1 17344   // padded row length for D1/D2/D3 (>=17325, mult of 64)
#define LD4 34688   // padded row length for D4 (>=34650, mult of 64)

#define GLP(p) ((const __attribute__((address_space(1))) void*)(p))
#define LDSP(p) ((__attribute__((address_space(3))) void*)(p))

__device__ __forceinline__ u16 f2b(float f) {
    union { float f; unsigned int u; } x;
    x.f = f;
    unsigned int r = x.u + 0x7FFFu + ((x.u >> 16) & 1u);
    return (u16)(r >> 16);
}
__device__ __forceinline__ float b2f(u16 u) {
    union { unsigned int u; float f; } x;
    x.u = ((unsigned int)u) << 16;
    return x.f;
}

// ---------------- LN (norm1): fp32 out + bf16 out ----------------
__global__ __launch_bounds__(256) void ln_kernel(const float* __restrict__ x,
                                                 const float* __restrict__ w,
                                                 const float* __restrict__ b,
                                                 float* __restrict__ y,
                                                 u16* __restrict__ y16) {
    __shared__ float red[256];
    int t = blockIdx.x;
    int tid = threadIdx.x;
    const float* row = x + (size_t)t * 768;
    float v0 = row[tid], v1 = row[tid + 256], v2 = row[tid + 512];
    red[tid] = v0 + v1 + v2;
    __syncthreads();
    for (int off = 128; off > 0; off >>= 1) {
        if (tid < off) red[tid] += red[tid + off];
        __syncthreads();
    }
    float mean = red[0] * (1.0f / 768.0f);
    __syncthreads();
    float d0 = v0 - mean, d1 = v1 - mean, d2 = v2 - mean;
    red[tid] = d0 * d0 + d1 * d1 + d2 * d2;
    __syncthreads();
    for (int off = 128; off > 0; off >>= 1) {
        if (tid < off) red[tid] += red[tid + off];
        __syncthreads();
    }
    float rstd = rsqrtf(red[0] * (1.0f / 768.0f) + 1e-5f);
    float* yr = y + (size_t)t * 768;
    u16* ys = y16 + (size_t)t * 768;
    float o0 = d0 * rstd * w[tid] + b[tid];
    float o1 = d1 * rstd * w[tid + 256] + b[tid + 256];
    float o2 = d2 * rstd * w[tid + 512] + b[tid + 512];
    yr[tid] = o0; yr[tid + 256] = o1; yr[tid + 512] = o2;
    ys[tid] = f2b(o0); ys[tid + 256] = f2b(o1); ys[tid + 512] = f2b(o2);
}

// ---------------- fused afno-combine + LN (norm2) ----------------
// mid = cur + tlnA + idht/SZ ; tlnB16 = bf16(LN(mid))
__global__ __launch_bounds__(256) void ln2c_kernel(const float* __restrict__ F4re,
                                                   const float* __restrict__ F4im,
                                                   const float* __restrict__ cur,
                                                   const float* __restrict__ tlnA,
                                                   const float* __restrict__ w,
                                                   const float* __restrict__ b,
                                                   float* __restrict__ mid,
                                                   u16* __restrict__ y16) {
    __shared__ float red[256];
    int t = blockIdx.x;
    int tid = threadIdx.x;
    int h = t / 90, w0 = t % 90;
    int h2 = (45 - h) % 45, w2 = (90 - w0) % 90;
    float vv[3];
#pragma unroll
    for (int s = 0; s < 3; s++) {
        int c = tid + s * 256;
        float v;
        if (c <= 384) {
            size_t g = (size_t)h * 34650 + (size_t)w0 * 385 + c;
            v = F4re[g] + F4im[g];
        } else {
            int k = 768 - c;
            size_t g = (size_t)h2 * 34650 + (size_t)w2 * 385 + k;
            v = F4re[g] - F4im[g];
        }
        size_t gi = (size_t)t * 768 + c;
        v = cur[gi] + tlnA[gi] + v * (1.0f / SZ_ALL);
        mid[gi] = v;
        vv[s] = v;
    }
    red[tid] = vv[0] + vv[1] + vv[2];
    __syncthreads();
    for (int off = 128; off > 0; off >>= 1) {
        if (tid < off) red[tid] += red[tid + off];
        __syncthreads();
    }
    float mean = red[0] * (1.0f / 768.0f);
    __syncthreads();
    float d0 = vv[0] - mean, d1 = vv[1] - mean, d2 = vv[2] - mean;
    red[tid] = d0 * d0 + d1 * d1 + d2 * d2;
    __syncthreads();
    for (int off = 128; off > 0; off >>= 1) {
        if (tid < off) red[tid] += red[tid + off];
        __syncthreads();
    }
    float rstd = rsqrtf(red[0] * (1.0f / 768.0f) + 1e-5f);
    u16* ys = y16 + (size_t)t * 768;
    ys[tid]       = f2b(d0 * rstd * w[tid] + b[tid]);
    ys[tid + 256] = f2b(d1 * rstd * w[tid + 256] + b[tid + 256]);
    ys[tid + 512] = f2b(d2 * rstd * w[tid + 512] + b[tid + 512]);
}

// ---------------- tables ----------------
__global__ __launch_bounds__(256) void init_tables(u16* TCc, u16* TCs, float* T_W1,
                                                   float* T_H, float* T_W2) {
    int gid = blockIdx.x * 256 + threadIdx.x;
    const double TP = 6.283185307179586476925286766559;
    if (gid < 385 * 768) {
        int n = gid / 768, c = gid % 768;
        int r = (n * c) % 768;
        double a = TP * (double)r / 768.0;
        TCc[(size_t)n * 768 + c] = f2b((float)cos(a));
        TCs[(size_t)n * 768 + c] = f2b((float)(-sin(a)));
    }
    if (gid < 90 * 192) {  // T_W1 [90][192]
        int m = gid / 192, kp = gid % 192;
        int j = m % 45, im = m / 45;
        int jf = j < 23 ? j : j + 45;
        float val = 0.f;
        if (kp < 90) {
            double a = TP * (double)((jf * kp) % 90) / 90.0;
            val = im ? (float)(-sin(a)) : (float)cos(a);
        } else if (kp < 180) {
            int ww = kp - 90;
            double a = TP * (double)((jf * ww) % 90) / 90.0;
            val = im ? (float)cos(a) : (float)sin(a);
        }
        T_W1[gid] = val;
    }
    if (gid < 90 * 96) {  // T_H [90][96]
        int m = gid / 96, kp = gid % 96;
        int i = m % 45, im = m / 45;
        float val = 0.f;
        if (kp < 45) {
            double a = TP * (double)((i * kp) % 45) / 45.0;
            val = im ? (float)(-sin(a)) : (float)cos(a);
        } else if (kp < 90) {
            int hh = kp - 45;
            double a = TP * (double)((i * hh) % 45) / 45.0;
            val = im ? (float)cos(a) : (float)sin(a);
        }
        T_H[gid] = val;
    }
    if (gid < 180 * 48) {  // T_W2 [180][48]
        int m = gid / 48, kp = gid % 48;
        int j = m % 90, im = m / 90;
        float val = 0.f;
        if (kp < 23) {
            double a = TP * (double)((j * kp) % 90) / 90.0;
            val = im ? (float)(-sin(a)) : (float)cos(a);
        } else if (kp < 46) {
            int ww = kp - 23;
            double a = TP * (double)((j * ww) % 90) / 90.0;
            val = im ? (float)cos(a) : (float)sin(a);
        }
        T_W2[gid] = val;
    }
}

// ---------------- casts ----------------
__global__ __launch_bounds__(256) void cast_f2b(const float* __restrict__ in,
                                                u16* __restrict__ out, int n) {
    int i = (blockIdx.x * 256 + threadIdx.x) * 4;
    if (i >= n) return;
    float4 v = *(const float4*)(in + i);
    out[i] = f2b(v.x); out[i + 1] = f2b(v.y); out[i + 2] = f2b(v.z); out[i + 3] = f2b(v.w);
}

__global__ __launch_bounds__(256) void cast_split(const float* __restrict__ in,
                                                  u16* __restrict__ hi,
                                                  u16* __restrict__ lo, int n) {
    int i = (blockIdx.x * 256 + threadIdx.x) * 4;
    if (i >= n) return;
    float4 v = *(const float4*)(in + i);
    float vs[4] = {v.x, v.y, v.z, v.w};
#pragma unroll
    for (int s = 0; s < 4; s++) {
        u16 h = f2b(vs[s]);
        hi[i + s] = h;
        lo[i + s] = f2b(vs[s] - b2f(h));
    }
}

// ---------------- patch gather: image -> bf16 A [NTOK][5120] ----------------
__global__ __launch_bounds__(256) void patch_gather(const float* __restrict__ img,
                                                    u16* __restrict__ A16) {
    int gid = blockIdx.x * 256 + threadIdx.x;  // one thread per 8 elems
    if (gid >= NTOK * 640) return;
    int t = gid / 640;
    int k8 = (gid - t * 640) * 8;
    int gh = t / 90, gw = t - gh * 90;
    int c = k8 >> 8, ph = (k8 >> 4) & 15, pw = k8 & 15;
    const float* p = img + (size_t)c * 1036800 + (size_t)(gh * 16 + ph) * 1440 + gw * 16 + pw;
    float4 u0 = *(const float4*)p;
    float4 u1 = *(const float4*)(p + 4);
    union { bf16x8 v; u16 s[8]; } o;
    o.s[0] = f2b(u0.x); o.s[1] = f2b(u0.y); o.s[2] = f2b(u0.z); o.s[3] = f2b(u0.w);
    o.s[4] = f2b(u1.x); o.s[5] = f2b(u1.y); o.s[6] = f2b(u1.z); o.s[7] = f2b(u1.w);
    *(bf16x8*)(A16 + (size_t)t * 5120 + k8) = o.v;
}

// ---------------- packed block-MLP weights ----------------
__global__ __launch_bounds__(256) void wpm_prep(const float* __restrict__ w1l,
                                                const float* __restrict__ w2l,
                                                u16* WB1k, u16* WB1n, u16* WB2, u16* WB2s) {
    int i = blockIdx.x * 256 + threadIdx.x;
    if (i >= 147456) return;
    int ii = i % 192;
    int o = (i / 192) % 96;
    int b = i / (192 * 96);
    int si = ii < 96 ? ii : ii - 96;
    size_t base = (size_t)b * 9216 + si * 96 + o;
    float p0 = w1l[base], p1 = w1l[73728 + base];
    float wp = 0.5f * (p0 + p1), wm = 0.5f * (p0 - p1);
    float q0 = w2l[base], q1 = w2l[73728 + base];
    float vp = 0.5f * (q0 + q1), vm = 0.5f * (q0 - q1);
    WB1k[i] = f2b(ii < 96 ? wp : wm);
    WB1n[i] = f2b(ii < 96 ? wm : wp);
    WB2[i] = f2b(ii < 96 ? vp : vm);
    WB2s[i] = f2b(ii < 96 ? vm : vp);
}

// ---------------- bf16 MFMA GEMM: out = A[M,K] * B[N,K]^T ----------------
// 3-deep software pipeline: counted vmcnt, raw barriers (never vmcnt(0) mid-loop).
// emode 0: fp32 direct  [m*ldout+n]
// emode 1: bf16 gelu(acc+bias)
// emode 2: fp32 acc+bias[n]+extra[m*ldout+n]
// emode 3: fp32 scatter g=(m%q)*ldd + (m/q)*385 + n   (DHT C-stage re-layout)
__global__ __launch_bounds__(256) void gemm_bf16(const u16* __restrict__ A,
                                                 const u16* __restrict__ B,
                                                 const float* __restrict__ bias,
                                                 const float* __restrict__ extra,
                                                 void* __restrict__ out,
                                                 int M, int N, int K, int ldout,
                                                 int emode, int q, int ldd) {
    __shared__ u16 As[3][4096];
    __shared__ u16 Bs[3][4096];
    int tid = threadIdx.x;
    int m0 = blockIdx.x * 128, n0 = blockIdx.y * 128;
    int srow = tid >> 2;
    int sk8 = (tid & 3) * 8;
    int ar0 = m0 + srow;        ar0 = ar0 < M ? ar0 : M - 1;
    int ar1 = m0 + 64 + srow;   ar1 = ar1 < M ? ar1 : M - 1;
    const u16* Ag0 = A + (size_t)ar0 * K + sk8;
    const u16* Ag1 = A + (size_t)ar1 * K + sk8;
    int br0 = n0 + srow;        br0 = br0 < N ? br0 : N - 1;
    int br1 = n0 + 64 + srow;   br1 = br1 < N ? br1 : N - 1;
    const u16* Bg0 = B + (size_t)br0 * K + sk8;
    const u16* Bg1 = B + (size_t)br1 * K + sk8;

    int lane = tid & 63, wave = tid >> 6;
    int wm = (wave & 1) * 64, wn = (wave >> 1) * 64;
    int lm = lane & 15, quad = lane >> 4;

    floatx4 acc[4][4];
    floatx4 z = {0.f, 0.f, 0.f, 0.f};
#pragma unroll
    for (int i = 0; i < 4; i++)
#pragma unroll
        for (int j = 0; j < 4; j++) acc[i][j] = z;

#define GSTAGE(tt, bb) do { int k0_ = (tt) * 32;                                             \
    __builtin_amdgcn_global_load_lds(GLP(Ag0 + k0_), LDSP(&As[bb][tid * 8]), 16, 0, 0);      \
    __builtin_amdgcn_global_load_lds(GLP(Ag1 + k0_), LDSP(&As[bb][2048 + tid * 8]), 16, 0, 0);\
    __builtin_amdgcn_global_load_lds(GLP(Bg0 + k0_), LDSP(&Bs[bb][tid * 8]), 16, 0, 0);      \
    __builtin_amdgcn_global_load_lds(GLP(Bg1 + k0_), LDSP(&Bs[bb][2048 + tid * 8]), 16, 0, 0);} while (0)

    int nt = K >> 5;
    GSTAGE(0, 0);
    if (nt > 1) GSTAGE(1, 1);
    if (nt > 2) GSTAGE(2, 2);
    int buf = 0;
    for (int t = 0; t < nt; t++) {
        int rem = nt - 1 - t;  // tiles in flight beyond t
        if (rem >= 2)      asm volatile("s_waitcnt vmcnt(8)" ::: "memory");
        else if (rem == 1) asm volatile("s_waitcnt vmcnt(4)" ::: "memory");
        else               asm volatile("s_waitcnt vmcnt(0)" ::: "memory");
        asm volatile("s_barrier" ::: "memory");
        bf16x8 af[4], bfr[4];
#pragma unroll
        for (int i = 0; i < 4; i++)
            af[i] = *(const bf16x8*)&As[buf][(wm + i * 16 + lm) * 32 + quad * 8];
#pragma unroll
        for (int j = 0; j < 4; j++)
            bfr[j] = *(const bf16x8*)&Bs[buf][(wn + j * 16 + lm) * 32 + quad * 8];
#pragma unroll
        for (int i = 0; i < 4; i++)
#pragma unroll
            for (int j = 0; j < 4; j++)
                acc[i][j] = __builtin_amdgcn_mfma_f32_16x16x32_bf16(af[i], bfr[j], acc[i][j], 0, 0, 0);
        asm volatile("s_barrier" ::: "memory");
        if (t + 3 < nt) GSTAGE(t + 3, buf);
        buf = (buf == 2) ? 0 : buf + 1;
    }
#undef GSTAGE

#pragma unroll
    for (int j = 0; j < 4; j++) {
        int n = n0 + wn + j * 16 + lm;
        if (n >= N) continue;
        float bn = (emode == 1 || emode == 2) ? bias[n] : 0.f;
#pragma unroll
        for (int i = 0; i < 4; i++) {
#pragma unroll
            for (int r = 0; r < 4; r++) {
                int m = m0 + wm + i * 16 + quad * 4 + r;
                if (m >= M) continue;
                float v = acc[i][j][r];
                if (emode == 0) {
                    ((float*)out)[(size_t)m * ldout + n] = v;
                } else if (emode == 1) {
                    v += bn;
                    float gl = 0.5f * v * (1.0f + erff(v * 0.70710678118654752f));
                    ((u16*)out)[(size_t)m * ldout + n] = f2b(gl);
                } else if (emode == 2) {
                    size_t g = (size_t)m * ldout + n;
                    ((float*)out)[g] = v + bn + extra[g];
                } else {
                    size_t g = (size_t)(m % q) * ldd + (size_t)(m / q) * 385 + n;
                    ((float*)out)[g] = v;
                }
            }
        }
    }
}

// ---------------- split-bf16 GEMM (head): out = (Ahi+Alo)(Bhi+Blo)^T, drop lo*lo ----------------
// 2-deep software pipeline. epilogue: head scatter to (20,720,1440)
__global__ __launch_bounds__(256) void gemm_split(const u16* __restrict__ Ahi,
                                                  const u16* __restrict__ Alo,
                                                  const u16* __restrict__ Bhi,
                                                  const u16* __restrict__ Blo,
                                                  float* __restrict__ out,
                                                  int M, int N, int K) {
    __shared__ u16 Ash[2][4096];
    __shared__ u16 Asl[2][4096];
    __shared__ u16 Bsh[2][4096];
    __shared__ u16 Bsl[2][4096];
    int tid = threadIdx.x;
    int m0 = blockIdx.x * 128, n0 = blockIdx.y * 128;
    int srow = tid >> 2, sk8 = (tid & 3) * 8;
    int ar0 = m0 + srow;        ar0 = ar0 < M ? ar0 : M - 1;
    int ar1 = m0 + 64 + srow;   ar1 = ar1 < M ? ar1 : M - 1;
    int br0 = n0 + srow;        br0 = br0 < N ? br0 : N - 1;
    int br1 = n0 + 64 + srow;   br1 = br1 < N ? br1 : N - 1;
    size_t a0 = (size_t)ar0 * K + sk8, a1 = (size_t)ar1 * K + sk8;
    size_t b0 = (size_t)br0 * K + sk8, b1 = (size_t)br1 * K + sk8;

    int lane = tid & 63, wave = tid >> 6;
    int wm = (wave & 1) * 64, wn = (wave >> 1) * 64;
    int lm = lane & 15, quad = lane >> 4;

    floatx4 acc[4][4];
    floatx4 z = {0.f, 0.f, 0.f, 0.f};
#pragma unroll
    for (int i = 0; i < 4; i++)
#pragma unroll
        for (int j = 0; j < 4; j++) acc[i][j] = z;

#define SSTAGE(tt, bb) do { int k0_ = (tt) * 32;                                               \
    __builtin_amdgcn_global_load_lds(GLP(Ahi + a0 + k0_), LDSP(&Ash[bb][tid * 8]), 16, 0, 0);  \
    __builtin_amdgcn_global_load_lds(GLP(Ahi + a1 + k0_), LDSP(&Ash[bb][2048 + tid * 8]), 16, 0, 0);\
    __builtin_amdgcn_global_load_lds(GLP(Alo + a0 + k0_), LDSP(&Asl[bb][tid * 8]), 16, 0, 0);  \
    __builtin_amdgcn_global_load_lds(GLP(Alo + a1 + k0_), LDSP(&Asl[bb][2048 + tid * 8]), 16, 0, 0);\
    __builtin_amdgcn_global_load_lds(GLP(Bhi + b0 + k0_), LDSP(&Bsh[bb][tid * 8]), 16, 0, 0);  \
    __builtin_amdgcn_global_load_lds(GLP(Bhi + b1 + k0_), LDSP(&Bsh[bb][2048 + tid * 8]), 16, 0, 0);\
    __builtin_amdgcn_global_load_lds(GLP(Blo + b0 + k0_), LDSP(&Bsl[bb][tid * 8]), 16, 0, 0);  \
    __builtin_amdgcn_global_load_lds(GLP(Blo + b1 + k0_), LDSP(&Bsl[bb][2048 + tid * 8]), 16, 0, 0);} while (0)

    int nt = K >> 5;
    SSTAGE(0, 0);
    if (nt > 1) SSTAGE(1, 1);
    int buf = 0;
    for (int t = 0; t < nt; t++) {
        int rem = nt - 1 - t;
        if (rem >= 1) asm volatile("s_waitcnt vmcnt(8)" ::: "memory");
        else          asm volatile("s_waitcnt vmcnt(0)" ::: "memory");
        asm volatile("s_barrier" ::: "memory");
        bf16x8 ah[4], al[4], bh[4], bl[4];
#pragma unroll
        for (int i = 0; i < 4; i++) {
            ah[i] = *(const bf16x8*)&Ash[buf][(wm + i * 16 + lm) * 32 + quad * 8];
            al[i] = *(const bf16x8*)&Asl[buf][(wm + i * 16 + lm) * 32 + quad * 8];
        }
#pragma unroll
        for (int j = 0; j < 4; j++) {
            bh[j] = *(const bf16x8*)&Bsh[buf][(wn + j * 16 + lm) * 32 + quad * 8];
            bl[j] = *(const bf16x8*)&Bsl[buf][(wn + j * 16 + lm) * 32 + quad * 8];
        }
#pragma unroll
        for (int i = 0; i < 4; i++)
#pragma unroll
            for (int j = 0; j < 4; j++) {
                acc[i][j] = __builtin_amdgcn_mfma_f32_16x16x32_bf16(al[i], bh[j], acc[i][j], 0, 0, 0);
                acc[i][j] = __builtin_amdgcn_mfma_f32_16x16x32_bf16(ah[i], bl[j], acc[i][j], 0, 0, 0);
                acc[i][j] = __builtin_amdgcn_mfma_f32_16x16x32_bf16(ah[i], bh[j], acc[i][j], 0, 0, 0);
            }
        asm volatile("s_barrier" ::: "memory");
        if (t + 2 < nt) SSTAGE(t + 2, buf);
        buf ^= 1;
    }
#undef SSTAGE

#pragma unroll
    for (int j = 0; j < 4; j++) {
        int n = n0 + wn + j * 16 + lm;
        if (n >= N) continue;
        int ch = n % 20, qq = n / 20;
        int pw = qq & 15, ph = qq >> 4;
#pragma unroll
        for (int i = 0; i < 4; i++) {
#pragma unroll
            for (int r = 0; r < 4; r++) {
                int m = m0 + wm + i * 16 + quad * 4 + r;
                if (m >= M) continue;
                int gh = m / 90, gw = m % 90;
                out[(size_t)ch * 1036800 + (size_t)(gh * 16 + ph) * 1440 + gw * 16 + pw] =
                    acc[i][j][r];
            }
        }
    }
}

// ---------------- fp32 DFT-stage GEMM: out = T[M,Kp] * D[Kp,N] ----------------
// scatter=0: g = m'*ldOut + n      (planes outA for m<M/2, outB for m>=M/2)
// scatter=1: g = (n/385)*ldOut + m'*385 + (n%385)
__global__ __launch_bounds__(256) void dft_gemm(const float* __restrict__ T,
                                                const float* __restrict__ D,
                                                float* __restrict__ outA,
                                                float* __restrict__ outB,
                                                int M, int N, int Kp, int ldD,
                                                int scatter, int ldOut) {
    __shared__ float Ts[16][68];
    __shared__ float Ds[16][132];
    int tid = threadIdx.x;
    int tx = tid & 15, ty = tid >> 4;
    int m0 = blockIdx.x * 64, n0 = blockIdx.y * 128;
    int lr = tid >> 2, lq = tid & 3;
    int dr = tid >> 4, dc = tid & 15;
    float acc[4][8] = {};
    for (int k0 = 0; k0 < Kp; k0 += 16) {
        int mr = m0 + lr; mr = mr < M ? mr : M - 1;
        float4 tv = *(const float4*)(T + (size_t)mr * Kp + k0 + lq * 4);
        Ts[lq * 4 + 0][lr] = tv.x;
        Ts[lq * 4 + 1][lr] = tv.y;
        Ts[lq * 4 + 2][lr] = tv.z;
        Ts[lq * 4 + 3][lr] = tv.w;
        const float* dp = D + (size_t)(k0 + dr) * ldD + n0 + dc * 4;
        float4 d0 = *(const float4*)dp;
        float4 d1 = *(const float4*)(dp + 64);
        Ds[dr][dc * 4 + 0] = d0.x; Ds[dr][dc * 4 + 1] = d0.y;
        Ds[dr][dc * 4 + 2] = d0.z; Ds[dr][dc * 4 + 3] = d0.w;
        Ds[dr][dc * 4 + 64] = d1.x; Ds[dr][dc * 4 + 65] = d1.y;
        Ds[dr][dc * 4 + 66] = d1.z; Ds[dr][dc * 4 + 67] = d1.w;
        __syncthreads();
#pragma unroll
        for (int kk = 0; kk < 16; kk++) {
            float a_[4], b_[8];
#pragma unroll
            for (int i = 0; i < 4; i++) a_[i] = Ts[kk][ty + 16 * i];
#pragma unroll
            for (int j = 0; j < 8; j++) b_[j] = Ds[kk][tx + 16 * j];
#pragma unroll
            for (int i = 0; i < 4; i++)
#pragma unroll
                for (int j = 0; j < 8; j++) acc[i][j] += a_[i] * b_[j];
        }
        __syncthreads();
    }
    int SP = M >> 1;
#pragma unroll
    for (int j = 0; j < 8; j++) {
        int n = n0 + tx + 16 * j;
        if (n >= N) continue;
        int h = n / 385, kk = n - h * 385;
#pragma unroll
        for (int i = 0; i < 4; i++) {
            int m = m0 + ty + 16 * i;
            if (m >= M) continue;
            int plane = m >= SP;
            int mp = plane ? m - SP : m;
            float* base = plane ? outB : outA;
            size_t g = scatter ? ((size_t)h * ldOut + (size_t)mp * 385 + kk)
                               : ((size_t)mp * ldOut + n);
            base[g] = acc[i][j];
        }
    }
}

// ---------------- build X = [a | n] per block (bf16) ----------------
__global__ __launch_bounds__(256) void build_an(const float* __restrict__ F3re,
                                                const float* __restrict__ F3im,
                                                const float* __restrict__ tln,
                                                u16* __restrict__ X) {
    int idx = blockIdx.x * 256 + threadIdx.x;
    if (idx >= NROW * 768) return;
    int c = idx % 768;
    int r = idx / 768;
    int h = r / KW, w0 = r % KW;
    int h2 = (45 - h) % 45, w2 = (90 - w0) % 90;
    float av;
    if (c <= 384) {
        size_t g = ((size_t)(h * 45 + w0)) * 385 + c;
        av = F3re[g] + F3im[g];
    } else {
        int k = 768 - c;
        int j2 = (w2 == 0) ? 0 : (w2 - 45);
        size_t g = ((size_t)(h2 * 45 + j2)) * 385 + k;
        av = F3re[g] - F3im[g];
    }
    float nv = tln[((size_t)(h2 * 90 + w2)) * 768 + c];
    int b = c / 96, o = c % 96;
    X[(size_t)r * 1536 + b * 192 + o] = f2b(av);
    X[(size_t)r * 1536 + b * 192 + 96 + o] = f2b(nv);
}

// ---------------- fused 3-stage block MLP (MFMA) ----------------
__global__ __launch_bounds__(256) void blk_fused(const u16* __restrict__ X,
                                                 const u16* __restrict__ WB1k,
                                                 const u16* __restrict__ WB1n,
                                                 const u16* __restrict__ WB2,
                                                 const u16* __restrict__ WB2s,
                                                 const float* __restrict__ b1l,
                                                 const float* __restrict__ b2l,
                                                 u16* __restrict__ ybuf16) {
    __shared__ u16 Ybuf[4][16 * 200];
    int b = blockIdx.x;
    int m0 = blockIdx.y * 64;
    int tid = threadIdx.x, lane = tid & 63, wave = tid >> 6;
    int lm = lane & 15, quad = lane >> 4;
    u16* Yw = &Ybuf[wave][0];

    int row = m0 + wave * 16 + lm;
    int rowc = row < NROW ? row : NROW - 1;
    const u16* Ab = X + (size_t)rowc * 1536 + b * 192;
    const u16* W1k = WB1k + (size_t)b * 18432;
    const u16* W1n = WB1n + (size_t)b * 18432;
    const u16* V2 = WB2 + (size_t)b * 18432;
    const u16* V2s = WB2s + (size_t)b * 18432;

    floatx4 z = {0.f, 0.f, 0.f, 0.f};
    floatx4 acc1[6], acc2[6];
#pragma unroll
    for (int j = 0; j < 6; j++) { acc1[j] = z; acc2[j] = z; }
    bf16x8 a[6];
#pragma unroll
    for (int k = 0; k < 6; k++) a[k] = *(const bf16x8*)(Ab + k * 32 + quad * 8);
#pragma unroll
    for (int k = 0; k < 6; k++)
#pragma unroll
        for (int j = 0; j < 6; j++) {
            bf16x8 w1 = *(const bf16x8*)(W1k + (size_t)(j * 16 + lm) * 192 + k * 32 + quad * 8);
            acc1[j] = __builtin_amdgcn_mfma_f32_16x16x32_bf16(a[k], w1, acc1[j], 0, 0, 0);
            bf16x8 w2 = *(const bf16x8*)(W1n + (size_t)(j * 16 + lm) * 192 + k * 32 + quad * 8);
            acc2[j] = __builtin_amdgcn_mfma_f32_16x16x32_bf16(a[k], w2, acc2[j], 0, 0, 0);
        }
    // stage1 epilogue -> Yw = [o1k | o1n]
#pragma unroll
    for (int j = 0; j < 6; j++) {
        int n = j * 16 + lm;
        float bA = b1l[b * 96 + n], bB = b1l[768 + b * 96 + n];
#pragma unroll
        for (int r = 0; r < 4; r++) {
            int mloc = quad * 4 + r;
            Yw[mloc * 200 + n] = f2b(fmaxf(acc1[j][r] + bA, 0.f));
            Yw[mloc * 200 + 96 + n] = f2b(fmaxf(acc2[j][r] + bB, 0.f));
        }
    }
    // stage2: o2k = [o1k|o1n]*[Vp|Vm] + b2k
    floatx4 acc3[6];
#pragma unroll
    for (int j = 0; j < 6; j++) acc3[j] = z;
    bf16x8 a2[6];
#pragma unroll
    for (int k = 0; k < 6; k++) a2[k] = *(const bf16x8*)(Yw + lm * 200 + k * 32 + quad * 8);
#pragma unroll
    for (int k = 0; k < 6; k++)
#pragma unroll
        for (int j = 0; j < 6; j++) {
            bf16x8 w = *(const bf16x8*)(V2 + (size_t)(j * 16 + lm) * 192 + k * 32 + quad * 8);
            acc3[j] = __builtin_amdgcn_mfma_f32_16x16x32_bf16(a2[k], w, acc3[j], 0, 0, 0);
        }
    float o2k[6][4];
#pragma unroll
    for (int j = 0; j < 6; j++) {
        int n = j * 16 + lm;
        float bA = b2l[b * 96 + n];
#pragma unroll
        for (int r = 0; r < 4; r++) {
            int mloc = quad * 4 + r;
            float v = acc3[j][r] + bA;
            o2k[j][r] = v;
            Yw[mloc * 200 + n] = f2b(v);  // Yw becomes [o2k | o1n]
        }
    }
    // stage3: o2n = [o2k|o1n]*[Vm|Vp] + b2n ; full = o2n + o2k ; soft-threshold
    floatx4 acc4[6];
#pragma unroll
    for (int j = 0; j < 6; j++) acc4[j] = z;
    bf16x8 a3[6];
#pragma unroll
    for (int k = 0; k < 6; k++) a3[k] = *(const bf16x8*)(Yw + lm * 200 + k * 32 + quad * 8);
#pragma unroll
    for (int k = 0; k < 6; k++)
#pragma unroll
        for (int j = 0; j < 6; j++) {
            bf16x8 w = *(const bf16x8*)(V2s + (size_t)(j * 16 + lm) * 192 + k * 32 + quad * 8);
            acc4[j] = __builtin_amdgcn_mfma_f32_16x16x32_bf16(a3[k], w, acc4[j], 0, 0, 0);
        }
#pragma unroll
    for (int j = 0; j < 6; j++) {
        int n = j * 16 + lm;
        float bB = b2l[768 + b * 96 + n];
#pragma unroll
        for (int r = 0; r < 4; r++) {
            int m = m0 + wave * 16 + quad * 4 + r;
            if (m >= NROW) continue;
            float full = acc4[j][r] + bB + o2k[j][r];
            float v = (full > LAMF) ? (full - LAMF) : ((full < -LAMF) ? (full + LAMF) : 0.f);
            ybuf16[(size_t)m * 768 + b * 96 + n] = f2b(v);
        }
    }
}

// ---------------- host ----------------
extern "C" void kernel_launch(void* const* d_in, const int* in_sizes, int n_in,
                              void* d_out, int out_size, void* d_ws, size_t ws_size,
                              hipStream_t stream) {
    const float* x       = (const float*)d_in[0];
    const float* patch_w = (const float*)d_in[1];
    const float* patch_b = (const float*)d_in[2];
    const float* pos     = (const float*)d_in[3];
    const float* n1w     = (const float*)d_in[4];
    const float* n1b     = (const float*)d_in[5];
    const float* w1      = (const float*)d_in[6];
    const float* b1      = (const float*)d_in[7];
    const float* w2      = (const float*)d_in[8];
    const float* b2      = (const float*)d_in[9];
    const float* n2w     = (const float*)d_in[10];
    const float* n2b     = (const float*)d_in[11];
    const float* fc1w    = (const float*)d_in[12];
    const float* fc1b    = (const float*)d_in[13];
    const float* fc2w    = (const float*)d_in[14];
    const float* fc2b    = (const float*)d_in[15];
    const float* headw   = (const float*)d_in[16];
    float* out = (float*)d_out;
    float* wsp = (float*)d_ws;

    size_t off = 0;
    auto af_ = [&](size_t n) { float* p = wsp + off; off += (n + 3) & ~(size_t)3; return p; };
    auto au_ = [&](size_t n) { u16* p = (u16*)(wsp + off); off += ((n + 1) / 2 + 3) & ~(size_t)3; return p; };

    u16* TCc = au_(512 * 768);
    u16* TCs = au_(512 * 768);
    float* T_W1 = af_(90 * 192);
    float* T_H  = af_(90 * 96);
    float* T_W2 = af_(180 * 48);
    u16* WB1k = au_(147456);
    u16* WB1n = au_(147456);
    u16* WB2  = au_(147456);
    u16* WB2s = au_(147456);
    u16* fc1w16 = au_(2359296);
    u16* fc2w16 = au_(2359296);
    float* cur = af_(3110400);
    float* mid = af_(3110400);
    float* tlnA = af_(3110400);
    u16* tlnA16 = au_(3110400);
    u16* tlnB16 = au_(3110400);
    u16* Xb = au_(1589760);
    u16* ybuf16 = au_(794880);
    float* F3re = af_(1559250);
    float* F3im = af_(1559250);
    float* F4re = af_(1559250);
    float* F4im = af_(1559250);
    float* SCR = af_(10368000);  // enlarged: holds patchA16 (20.74M u16) in patch phase
    // DFT scratch inside SCR
    float* D1 = SCR;                         // [192][LD1]   (90 xr + 90 xi + pad)
    float* D2 = D1 + (size_t)192 * LD1;      // [96][LD1]    (45 xr + 45 xi + pad)
    float* D3 = D2 + (size_t)96 * LD1;       // [48][LD1]    (23 xr + 23 xi + pad)
    float* D4 = D3 + (size_t)48 * LD1;       // [96][LD4]    (45 xr + 45 xi + pad)
    u16* hidden16 = (u16*)SCR;               // 12.44M u16 = 6.22M f (MLP phase)
    u16* patchA16 = (u16*)SCR;               // patch phase: gathered A [4050][5120] bf16
    u16* pw16 = fc1w16;                      // patch phase: patch weights (spans fc1w16+fc2w16)
    u16* Chi = (u16*)SCR;                    // head phase
    u16* Clo = Chi + 3110400;
    u16* Hhi = Clo + 3110400;
    u16* Hlo = Hhi + 3932160;
    size_t need = off * sizeof(float);
    if (ws_size < need) return;

    init_tables<<<1536, 256, 0, stream>>>(TCc, TCs, T_W1, T_H, T_W2);

    // ---- patch embed: gather image -> bf16 A, then pipelined MFMA GEMM ----
    cast_f2b<<<3840, 256, 0, stream>>>(patch_w, pw16, 3932160);
    patch_gather<<<10125, 256, 0, stream>>>(x, patchA16);
    gemm_bf16<<<dim3(32, 6), 256, 0, stream>>>(patchA16, pw16, patch_b, pos, cur,
                                               NTOK, 768, 5120, 768, 2, 0, 0);

    for (int l = 0; l < 12; l++) {
        const float* w1l = w1 + (size_t)l * 147456;
        const float* b1l = b1 + (size_t)l * 1536;
        const float* w2l = w2 + (size_t)l * 147456;
        const float* b2l = b2 + (size_t)l * 1536;

        cast_f2b<<<2304, 256, 0, stream>>>(fc1w + (size_t)l * 2359296, fc1w16, 2359296);
        cast_f2b<<<2304, 256, 0, stream>>>(fc2w + (size_t)l * 2359296, fc2w16, 2359296);
        wpm_prep<<<576, 256, 0, stream>>>(w1l, w2l, WB1k, WB1n, WB2, WB2s);
        ln_kernel<<<NTOK, 256, 0, stream>>>(cur, n1w + l * 768, n1b + l * 768, tlnA, tlnA16);

        // DHT1: C-axis DFT -> D1 [w][h][k] layout (re/im planes)
        gemm_bf16<<<dim3(32, 4), 256, 0, stream>>>(tlnA16, TCc, nullptr, nullptr, D1,
                                                   NTOK, 385, 768, 0, 3, 90, LD1);
        gemm_bf16<<<dim3(32, 4), 256, 0, stream>>>(tlnA16, TCs, nullptr, nullptr,
                                                   D1 + (size_t)90 * LD1,
                                                   NTOK, 385, 768, 0, 3, 90, LD1);
        // W-axis (90 -> 45 selected) -> D2 [h][j][k]
        dft_gemm<<<dim3(2, 136), 256, 0, stream>>>(T_W1, D1, D2, D2 + (size_t)45 * LD1,
                                                   90, 17325, 192, LD1, 1, LD1);
        // H-axis (45 -> 45) -> F3 planes [i][j][k]
        dft_gemm<<<dim3(2, 136), 256, 0, stream>>>(T_H, D2, F3re, F3im,
                                                   90, 17325, 96, LD1, 0, 17325);
        build_an<<<(NROW * 768 + 255) / 256, 256, 0, stream>>>(F3re, F3im, tlnA, Xb);

        // fused block MLP
        blk_fused<<<dim3(8, 17), 256, 0, stream>>>(Xb, WB1k, WB1n, WB2, WB2s,
                                                   b1l, b2l, ybuf16);

        // DHT2: C-axis DFT -> D3 [w0][h][k]
        gemm_bf16<<<dim3(9, 4), 256, 0, stream>>>(ybuf16, TCc, nullptr, nullptr, D3,
                                                  NROW, 385, 768, 0, 3, 23, LD1);
        gemm_bf16<<<dim3(9, 4), 256, 0, stream>>>(ybuf16, TCs, nullptr, nullptr,
                                                  D3 + (size_t)23 * LD1,
                                                  NROW, 385, 768, 0, 3, 23, LD1);
        // W-axis (23 -> 90) -> D4 [h][j][k]
        dft_gemm<<<dim3(3, 136), 256, 0, stream>>>(T_W2, D3, D4, D4 + (size_t)45 * LD4,
                                                   180, 17325, 48, LD1, 1, LD4);
        // H-axis (45 -> 45) -> F4 planes [i][j][k]
        dft_gemm<<<dim3(2, 271), 256, 0, stream>>>(T_H, D4, F4re, F4im,
                                                   90, 34650, 96, LD4, 0, 34650);
        // combine + LN2 fused
        ln2c_kernel<<<NTOK, 256, 0, stream>>>(F4re, F4im, cur, tlnA,
                                              n2w + l * 768, n2b + l * 768, mid, tlnB16);

        // MLP
        gemm_bf16<<<dim3(32, 24), 256, 0, stream>>>(tlnB16, fc1w16, fc1b + l * 3072, nullptr,
                                                    hidden16, NTOK, 3072, 768, 3072, 1, 0, 0);
        gemm_bf16<<<dim3(32, 6), 256, 0, stream>>>(hidden16, fc2w16, fc2b + l * 768, mid,
                                                   cur, NTOK, 768, 3072, 768, 2, 0, 0);
    }

    // ---- head: split-bf16 GEMM + scatter ----
    cast_split<<<3038, 256, 0, stream>>>(cur, Chi, Clo, 3110400);
    cast_split<<<3840, 256, 0, stream>>>(headw, Hhi, Hlo, 3932160);
    gemm_split<<<dim3(32, 40), 256, 0, stream>>>(Chi, Clo, Hhi, Hlo, out,
                                                 NTOK, 5120, 768);
}

// Round 2
// 4673.759 us; speedup vs baseline: 1.3263x; 1.1648x over previous
//
#include <hip/hip_runtime.h>
#include <math.h>

typedef __attribute__((ext_vector_type(4))) float floatx4;
typedef __attribute__((ext_vector_type(8))) short bf16x8;
typedef unsigned short u16;

#define NTOK 4050
#define KW 23
#define NROW 1035
#define SZ_ALL 3110400.0f
#define LAMF 0.01f
#define LD1 17344   // padded row length for D1/D2/D3 (>=17325, mult of 64)
#define LD4 34688   // padded row length for D4 (>=34650, mult of 64)

#define GLP(p) ((const __attribute__((address_space(1))) void*)(p))
#define LDSP(p) ((__attribute__((address_space(3))) void*)(p))

__device__ __forceinline__ u16 f2b(float f) {
    union { float f; unsigned int u; } x;
    x.f = f;
    unsigned int r = x.u + 0x7FFFu + ((x.u >> 16) & 1u);
    return (u16)(r >> 16);
}
__device__ __forceinline__ float b2f(u16 u) {
    union { unsigned int u; float f; } x;
    x.u = ((unsigned int)u) << 16;
    return x.f;
}

// ---------------- LN (norm1): fp32 out + bf16 out ----------------
__global__ __launch_bounds__(256) void ln_kernel(const float* __restrict__ x,
                                                 const float* __restrict__ w,
                                                 const float* __restrict__ b,
                                                 float* __restrict__ y,
                                                 u16* __restrict__ y16) {
    __shared__ float red[256];
    int t = blockIdx.x;
    int tid = threadIdx.x;
    const float* row = x + (size_t)t * 768;
    float v0 = row[tid], v1 = row[tid + 256], v2 = row[tid + 512];
    red[tid] = v0 + v1 + v2;
    __syncthreads();
    for (int off = 128; off > 0; off >>= 1) {
        if (tid < off) red[tid] += red[tid + off];
        __syncthreads();
    }
    float mean = red[0] * (1.0f / 768.0f);
    __syncthreads();
    float d0 = v0 - mean, d1 = v1 - mean, d2 = v2 - mean;
    red[tid] = d0 * d0 + d1 * d1 + d2 * d2;
    __syncthreads();
    for (int off = 128; off > 0; off >>= 1) {
        if (tid < off) red[tid] += red[tid + off];
        __syncthreads();
    }
    float rstd = rsqrtf(red[0] * (1.0f / 768.0f) + 1e-5f);
    float* yr = y + (size_t)t * 768;
    u16* ys = y16 + (size_t)t * 768;
    float o0 = d0 * rstd * w[tid] + b[tid];
    float o1 = d1 * rstd * w[tid + 256] + b[tid + 256];
    float o2 = d2 * rstd * w[tid + 512] + b[tid + 512];
    yr[tid] = o0; yr[tid + 256] = o1; yr[tid + 512] = o2;
    ys[tid] = f2b(o0); ys[tid + 256] = f2b(o1); ys[tid + 512] = f2b(o2);
}

// ---------------- fused afno-combine + LN (norm2) ----------------
__global__ __launch_bounds__(256) void ln2c_kernel(const float* __restrict__ F4re,
                                                   const float* __restrict__ F4im,
                                                   const float* __restrict__ cur,
                                                   const float* __restrict__ tlnA,
                                                   const float* __restrict__ w,
                                                   const float* __restrict__ b,
                                                   float* __restrict__ mid,
                                                   u16* __restrict__ y16) {
    __shared__ float red[256];
    int t = blockIdx.x;
    int tid = threadIdx.x;
    int h = t / 90, w0 = t % 90;
    int h2 = (45 - h) % 45, w2 = (90 - w0) % 90;
    float vv[3];
#pragma unroll
    for (int s = 0; s < 3; s++) {
        int c = tid + s * 256;
        float v;
        if (c <= 384) {
            size_t g = (size_t)h * 34650 + (size_t)w0 * 385 + c;
            v = F4re[g] + F4im[g];
        } else {
            int k = 768 - c;
            size_t g = (size_t)h2 * 34650 + (size_t)w2 * 385 + k;
            v = F4re[g] - F4im[g];
        }
        size_t gi = (size_t)t * 768 + c;
        v = cur[gi] + tlnA[gi] + v * (1.0f / SZ_ALL);
        mid[gi] = v;
        vv[s] = v;
    }
    red[tid] = vv[0] + vv[1] + vv[2];
    __syncthreads();
    for (int off = 128; off > 0; off >>= 1) {
        if (tid < off) red[tid] += red[tid + off];
        __syncthreads();
    }
    float mean = red[0] * (1.0f / 768.0f);
    __syncthreads();
    float d0 = vv[0] - mean, d1 = vv[1] - mean, d2 = vv[2] - mean;
    red[tid] = d0 * d0 + d1 * d1 + d2 * d2;
    __syncthreads();
    for (int off = 128; off > 0; off >>= 1) {
        if (tid < off) red[tid] += red[tid + off];
        __syncthreads();
    }
    float rstd = rsqrtf(red[0] * (1.0f / 768.0f) + 1e-5f);
    u16* ys = y16 + (size_t)t * 768;
    ys[tid]       = f2b(d0 * rstd * w[tid] + b[tid]);
    ys[tid + 256] = f2b(d1 * rstd * w[tid + 256] + b[tid + 256]);
    ys[tid + 512] = f2b(d2 * rstd * w[tid + 512] + b[tid + 512]);
}

// ---------------- tables ----------------
// TCcs: stacked [770][768]; rows 0..384 = cos table, rows 385..769 = -sin table
__global__ __launch_bounds__(256) void init_tables(u16* TCcs, float* T_W1,
                                                   float* T_H, float* T_W2) {
    int gid = blockIdx.x * 256 + threadIdx.x;
    const double TP = 6.283185307179586476925286766559;
    if (gid < 770 * 768) {
        int n = gid / 768, c = gid % 768;
        int f = n < 385 ? n : n - 385;
        int r = (f * c) % 768;
        double a = TP * (double)r / 768.0;
        TCcs[gid] = f2b(n < 385 ? (float)cos(a) : (float)(-sin(a)));
    }
    if (gid < 90 * 192) {  // T_W1 [90][192]
        int m = gid / 192, kp = gid % 192;
        int j = m % 45, im = m / 45;
        int jf = j < 23 ? j : j + 45;
        float val = 0.f;
        if (kp < 90) {
            double a = TP * (double)((jf * kp) % 90) / 90.0;
            val = im ? (float)(-sin(a)) : (float)cos(a);
        } else if (kp < 180) {
            int ww = kp - 90;
            double a = TP * (double)((jf * ww) % 90) / 90.0;
            val = im ? (float)cos(a) : (float)sin(a);
        }
        T_W1[gid] = val;
    }
    if (gid < 90 * 96) {  // T_H [90][96]
        int m = gid / 96, kp = gid % 96;
        int i = m % 45, im = m / 45;
        float val = 0.f;
        if (kp < 45) {
            double a = TP * (double)((i * kp) % 45) / 45.0;
            val = im ? (float)(-sin(a)) : (float)cos(a);
        } else if (kp < 90) {
            int hh = kp - 45;
            double a = TP * (double)((i * hh) % 45) / 45.0;
            val = im ? (float)cos(a) : (float)sin(a);
        }
        T_H[gid] = val;
    }
    if (gid < 180 * 48) {  // T_W2 [180][48]
        int m = gid / 48, kp = gid % 48;
        int j = m % 90, im = m / 90;
        float val = 0.f;
        if (kp < 23) {
            double a = TP * (double)((j * kp) % 90) / 90.0;
            val = im ? (float)(-sin(a)) : (float)cos(a);
        } else if (kp < 46) {
            int ww = kp - 23;
            double a = TP * (double)((j * ww) % 90) / 90.0;
            val = im ? (float)cos(a) : (float)sin(a);
        }
        T_W2[gid] = val;
    }
}

// ---------------- casts ----------------
__global__ __launch_bounds__(256) void cast_f2b(const float* __restrict__ in,
                                                u16* __restrict__ out, int n) {
    int i = (blockIdx.x * 256 + threadIdx.x) * 4;
    if (i >= n) return;
    float4 v = *(const float4*)(in + i);
    out[i] = f2b(v.x); out[i + 1] = f2b(v.y); out[i + 2] = f2b(v.z); out[i + 3] = f2b(v.w);
}

// two independent casts fused in one dispatch (saves launches per layer)
__global__ __launch_bounds__(256) void cast2_f2b(const float* __restrict__ in1,
                                                 const float* __restrict__ in2,
                                                 u16* __restrict__ out1,
                                                 u16* __restrict__ out2, int n) {
    int i = (blockIdx.x * 256 + threadIdx.x) * 4;
    const float* in = in1;
    u16* out = out1;
    if (i >= n) { in = in2; out = out2; i -= n; }
    if (i >= n) return;
    float4 v = *(const float4*)(in + i);
    out[i] = f2b(v.x); out[i + 1] = f2b(v.y); out[i + 2] = f2b(v.z); out[i + 3] = f2b(v.w);
}

__global__ __launch_bounds__(256) void cast_split(const float* __restrict__ in,
                                                  u16* __restrict__ hi,
                                                  u16* __restrict__ lo, int n) {
    int i = (blockIdx.x * 256 + threadIdx.x) * 4;
    if (i >= n) return;
    float4 v = *(const float4*)(in + i);
    float vs[4] = {v.x, v.y, v.z, v.w};
#pragma unroll
    for (int s = 0; s < 4; s++) {
        u16 h = f2b(vs[s]);
        hi[i + s] = h;
        lo[i + s] = f2b(vs[s] - b2f(h));
    }
}

// head weights: split + row permutation  o=ph*320+pw*20+ch -> o'=ch*256+ph*16+pw
// so that consecutive GEMM columns n are consecutive pw (coalesced image stores)
__global__ __launch_bounds__(256) void cast_split_perm(const float* __restrict__ in,
                                                       u16* __restrict__ hi,
                                                       u16* __restrict__ lo) {
    int i = (blockIdx.x * 256 + threadIdx.x) * 4;
    if (i >= 3932160) return;
    int o = i / 768, c = i % 768;
    int ch = o % 20, qq = o / 20;
    int pw = qq & 15, ph = qq >> 4;
    size_t dst = (size_t)(ch * 256 + ph * 16 + pw) * 768 + c;
    float4 v = *(const float4*)(in + i);
    float vs[4] = {v.x, v.y, v.z, v.w};
#pragma unroll
    for (int s = 0; s < 4; s++) {
        u16 h = f2b(vs[s]);
        hi[dst + s] = h;
        lo[dst + s] = f2b(vs[s] - b2f(h));
    }
}

// ---------------- patch gather: image -> bf16 A [NTOK][5120] ----------------
__global__ __launch_bounds__(256) void patch_gather(const float* __restrict__ img,
                                                    u16* __restrict__ A16) {
    int gid = blockIdx.x * 256 + threadIdx.x;  // one thread per 8 elems
    if (gid >= NTOK * 640) return;
    int t = gid / 640;
    int k8 = (gid - t * 640) * 8;
    int gh = t / 90, gw = t - gh * 90;
    int c = k8 >> 8, ph = (k8 >> 4) & 15, pw = k8 & 15;
    const float* p = img + (size_t)c * 1036800 + (size_t)(gh * 16 + ph) * 1440 + gw * 16 + pw;
    float4 u0 = *(const float4*)p;
    float4 u1 = *(const float4*)(p + 4);
    union { bf16x8 v; u16 s[8]; } o;
    o.s[0] = f2b(u0.x); o.s[1] = f2b(u0.y); o.s[2] = f2b(u0.z); o.s[3] = f2b(u0.w);
    o.s[4] = f2b(u1.x); o.s[5] = f2b(u1.y); o.s[6] = f2b(u1.z); o.s[7] = f2b(u1.w);
    *(bf16x8*)(A16 + (size_t)t * 5120 + k8) = o.v;
}

// ---------------- packed block-MLP weights ----------------
__global__ __launch_bounds__(256) void wpm_prep(const float* __restrict__ w1l,
                                                const float* __restrict__ w2l,
                                                u16* WB1k, u16* WB1n, u16* WB2, u16* WB2s) {
    int i = blockIdx.x * 256 + threadIdx.x;
    if (i >= 147456) return;
    int ii = i % 192;
    int o = (i / 192) % 96;
    int b = i / (192 * 96);
    int si = ii < 96 ? ii : ii - 96;
    size_t base = (size_t)b * 9216 + si * 96 + o;
    float p0 = w1l[base], p1 = w1l[73728 + base];
    float wp = 0.5f * (p0 + p1), wm = 0.5f * (p0 - p1);
    float q0 = w2l[base], q1 = w2l[73728 + base];
    float vp = 0.5f * (q0 + q1), vm = 0.5f * (q0 - q1);
    WB1k[i] = f2b(ii < 96 ? wp : wm);
    WB1n[i] = f2b(ii < 96 ? wm : wp);
    WB2[i] = f2b(ii < 96 ? vp : vm);
    WB2s[i] = f2b(ii < 96 ? vm : vp);
}

// ---------------- bf16 MFMA GEMM: out = A[M,K] * B[N,K]^T ----------------
// 3-deep software pipeline, counted vmcnt; LDS XOR-swizzled (4-way -> fewer conflicts):
// global source chunk pre-swizzled so global_load_lds dest stays linear (rule #21).
// emode 0: fp32 direct  [m*ldout+n]
// emode 1: bf16 gelu(acc+bias)
// emode 2: fp32 acc+bias[n]+extra[m*ldout+n]
// emode 3: fp32 scatter, merged cos/sin planes: plane=n>=385, col=n-385*plane,
//          g=(m%q)*ldd + (m/q)*385 + col + plane*ldout   (ldout = plane offset)
__global__ __launch_bounds__(256) void gemm_bf16(const u16* __restrict__ A,
                                                 const u16* __restrict__ B,
                                                 const float* __restrict__ bias,
                                                 const float* __restrict__ extra,
                                                 void* __restrict__ out,
                                                 int M, int N, int K, int ldout,
                                                 int emode, int q, int ldd) {
    __shared__ u16 As[3][4096];
    __shared__ u16 Bs[3][4096];
    int tid = threadIdx.x;
    int m0 = blockIdx.x * 128, n0 = blockIdx.y * 128;
    int srow = tid >> 2;
    int sk8 = (((tid & 3) ^ (srow & 3))) * 8;   // pre-swizzled source chunk
    int ar0 = m0 + srow;        ar0 = ar0 < M ? ar0 : M - 1;
    int ar1 = m0 + 64 + srow;   ar1 = ar1 < M ? ar1 : M - 1;
    const u16* Ag0 = A + (size_t)ar0 * K + sk8;
    const u16* Ag1 = A + (size_t)ar1 * K + sk8;
    int br0 = n0 + srow;        br0 = br0 < N ? br0 : N - 1;
    int br1 = n0 + 64 + srow;   br1 = br1 < N ? br1 : N - 1;
    const u16* Bg0 = B + (size_t)br0 * K + sk8;
    const u16* Bg1 = B + (size_t)br1 * K + sk8;

    int lane = tid & 63, wave = tid >> 6;
    int wm = (wave & 1) * 64, wn = (wave >> 1) * 64;
    int lm = lane & 15, quad = lane >> 4;
    int swr = (quad ^ (lm & 3)) * 8;            // swizzled read slot

    floatx4 acc[4][4];
    floatx4 z = {0.f, 0.f, 0.f, 0.f};
#pragma unroll
    for (int i = 0; i < 4; i++)
#pragma unroll
        for (int j = 0; j < 4; j++) acc[i][j] = z;

#define GSTAGE(tt, bb) do { int k0_ = (tt) * 32;                                             \
    __builtin_amdgcn_global_load_lds(GLP(Ag0 + k0_), LDSP(&As[bb][tid * 8]), 16, 0, 0);      \
    __builtin_amdgcn_global_load_lds(GLP(Ag1 + k0_), LDSP(&As[bb][2048 + tid * 8]), 16, 0, 0);\
    __builtin_amdgcn_global_load_lds(GLP(Bg0 + k0_), LDSP(&Bs[bb][tid * 8]), 16, 0, 0);      \
    __builtin_amdgcn_global_load_lds(GLP(Bg1 + k0_), LDSP(&Bs[bb][2048 + tid * 8]), 16, 0, 0);} while (0)

    int nt = K >> 5;
    GSTAGE(0, 0);
    if (nt > 1) GSTAGE(1, 1);
    if (nt > 2) GSTAGE(2, 2);
    int buf = 0;
    for (int t = 0; t < nt; t++) {
        int rem = nt - 1 - t;  // tiles in flight beyond t
        if (rem >= 2)      asm volatile("s_waitcnt vmcnt(8)" ::: "memory");
        else if (rem == 1) asm volatile("s_waitcnt vmcnt(4)" ::: "memory");
        else               asm volatile("s_waitcnt vmcnt(0)" ::: "memory");
        asm volatile("s_barrier" ::: "memory");
        bf16x8 af[4], bfr[4];
#pragma unroll
        for (int i = 0; i < 4; i++)
            af[i] = *(const bf16x8*)&As[buf][(wm + i * 16 + lm) * 32 + swr];
#pragma unroll
        for (int j = 0; j < 4; j++)
            bfr[j] = *(const bf16x8*)&Bs[buf][(wn + j * 16 + lm) * 32 + swr];
#pragma unroll
        for (int i = 0; i < 4; i++)
#pragma unroll
            for (int j = 0; j < 4; j++)
                acc[i][j] = __builtin_amdgcn_mfma_f32_16x16x32_bf16(af[i], bfr[j], acc[i][j], 0, 0, 0);
        asm volatile("s_barrier" ::: "memory");
        if (t + 3 < nt) GSTAGE(t + 3, buf);
        buf = (buf == 2) ? 0 : buf + 1;
    }
#undef GSTAGE

#pragma unroll
    for (int j = 0; j < 4; j++) {
        int n = n0 + wn + j * 16 + lm;
        if (n >= N) continue;
        float bn = (emode == 1 || emode == 2) ? bias[n] : 0.f;
#pragma unroll
        for (int i = 0; i < 4; i++) {
#pragma unroll
            for (int r = 0; r < 4; r++) {
                int m = m0 + wm + i * 16 + quad * 4 + r;
                if (m >= M) continue;
                float v = acc[i][j][r];
                if (emode == 0) {
                    ((float*)out)[(size_t)m * ldout + n] = v;
                } else if (emode == 1) {
                    v += bn;
                    float gl = 0.5f * v * (1.0f + erff(v * 0.70710678118654752f));
                    ((u16*)out)[(size_t)m * ldout + n] = f2b(gl);
                } else if (emode == 2) {
                    size_t g = (size_t)m * ldout + n;
                    ((float*)out)[g] = v + bn + extra[g];
                } else {
                    int plane = n >= 385;
                    int col = plane ? n - 385 : n;
                    size_t g = (size_t)(m % q) * ldd + (size_t)(m / q) * 385 + col
                             + (plane ? (size_t)ldout : (size_t)0);
                    ((float*)out)[g] = v;
                }
            }
        }
    }
}

// ---------------- split-bf16 GEMM (head): out = (Ahi+Alo)(Bhi+Blo)^T, drop lo*lo ----------------
// 2-deep pipeline, LDS swizzle; B rows pre-permuted so epilogue decode n=ch*256+ph*16+pw
// gives fully coalesced 64B image stores.
__global__ __launch_bounds__(256) void gemm_split(const u16* __restrict__ Ahi,
                                                  const u16* __restrict__ Alo,
                                                  const u16* __restrict__ Bhi,
                                                  const u16* __restrict__ Blo,
                                                  float* __restrict__ out,
                                                  int M, int N, int K) {
    __shared__ u16 Ash[2][4096];
    __shared__ u16 Asl[2][4096];
    __shared__ u16 Bsh[2][4096];
    __shared__ u16 Bsl[2][4096];
    int tid = threadIdx.x;
    int m0 = blockIdx.x * 128, n0 = blockIdx.y * 128;
    int srow = tid >> 2;
    int sk8 = (((tid & 3) ^ (srow & 3))) * 8;
    int ar0 = m0 + srow;        ar0 = ar0 < M ? ar0 : M - 1;
    int ar1 = m0 + 64 + srow;   ar1 = ar1 < M ? ar1 : M - 1;
    int br0 = n0 + srow;        br0 = br0 < N ? br0 : N - 1;
    int br1 = n0 + 64 + srow;   br1 = br1 < N ? br1 : N - 1;
    size_t a0 = (size_t)ar0 * K + sk8, a1 = (size_t)ar1 * K + sk8;
    size_t b0 = (size_t)br0 * K + sk8, b1 = (size_t)br1 * K + sk8;

    int lane = tid & 63, wave = tid >> 6;
    int wm = (wave & 1) * 64, wn = (wave >> 1) * 64;
    int lm = lane & 15, quad = lane >> 4;
    int swr = (quad ^ (lm & 3)) * 8;

    floatx4 acc[4][4];
    floatx4 z = {0.f, 0.f, 0.f, 0.f};
#pragma unroll
    for (int i = 0; i < 4; i++)
#pragma unroll
        for (int j = 0; j < 4; j++) acc[i][j] = z;

#define SSTAGE(tt, bb) do { int k0_ = (tt) * 32;                                               \
    __builtin_amdgcn_global_load_lds(GLP(Ahi + a0 + k0_), LDSP(&Ash[bb][tid * 8]), 16, 0, 0);  \
    __builtin_amdgcn_global_load_lds(GLP(Ahi + a1 + k0_), LDSP(&Ash[bb][2048 + tid * 8]), 16, 0, 0);\
    __builtin_amdgcn_global_load_lds(GLP(Alo + a0 + k0_), LDSP(&Asl[bb][tid * 8]), 16, 0, 0);  \
    __builtin_amdgcn_global_load_lds(GLP(Alo + a1 + k0_), LDSP(&Asl[bb][2048 + tid * 8]), 16, 0, 0);\
    __builtin_amdgcn_global_load_lds(GLP(Bhi + b0 + k0_), LDSP(&Bsh[bb][tid * 8]), 16, 0, 0);  \
    __builtin_amdgcn_global_load_lds(GLP(Bhi + b1 + k0_), LDSP(&Bsh[bb][2048 + tid * 8]), 16, 0, 0);\
    __builtin_amdgcn_global_load_lds(GLP(Blo + b0 + k0_), LDSP(&Bsl[bb][tid * 8]), 16, 0, 0);  \
    __builtin_amdgcn_global_load_lds(GLP(Blo + b1 + k0_), LDSP(&Bsl[bb][2048 + tid * 8]), 16, 0, 0);} while (0)

    int nt = K >> 5;
    SSTAGE(0, 0);
    if (nt > 1) SSTAGE(1, 1);
    int buf = 0;
    for (int t = 0; t < nt; t++) {
        int rem = nt - 1 - t;
        if (rem >= 1) asm volatile("s_waitcnt vmcnt(8)" ::: "memory");
        else          asm volatile("s_waitcnt vmcnt(0)" ::: "memory");
        asm volatile("s_barrier" ::: "memory");
        bf16x8 ah[4], al[4], bh[4], bl[4];
#pragma unroll
        for (int i = 0; i < 4; i++) {
            ah[i] = *(const bf16x8*)&Ash[buf][(wm + i * 16 + lm) * 32 + swr];
            al[i] = *(const bf16x8*)&Asl[buf][(wm + i * 16 + lm) * 32 + swr];
        }
#pragma unroll
        for (int j = 0; j < 4; j++) {
            bh[j] = *(const bf16x8*)&Bsh[buf][(wn + j * 16 + lm) * 32 + swr];
            bl[j] = *(const bf16x8*)&Bsl[buf][(wn + j * 16 + lm) * 32 + swr];
        }
#pragma unroll
        for (int i = 0; i < 4; i++)
#pragma unroll
            for (int j = 0; j < 4; j++) {
                acc[i][j] = __builtin_amdgcn_mfma_f32_16x16x32_bf16(al[i], bh[j], acc[i][j], 0, 0, 0);
                acc[i][j] = __builtin_amdgcn_mfma_f32_16x16x32_bf16(ah[i], bl[j], acc[i][j], 0, 0, 0);
                acc[i][j] = __builtin_amdgcn_mfma_f32_16x16x32_bf16(ah[i], bh[j], acc[i][j], 0, 0, 0);
            }
        asm volatile("s_barrier" ::: "memory");
        if (t + 2 < nt) SSTAGE(t + 2, buf);
        buf ^= 1;
    }
#undef SSTAGE

#pragma unroll
    for (int j = 0; j < 4; j++) {
        int n = n0 + wn + j * 16 + lm;
        if (n >= N) continue;
        int ch = n >> 8;                  // permuted decode
        int ph = (n >> 4) & 15, pw = n & 15;
#pragma unroll
        for (int i = 0; i < 4; i++) {
#pragma unroll
            for (int r = 0; r < 4; r++) {
                int m = m0 + wm + i * 16 + quad * 4 + r;
                if (m >= M) continue;
                int gh = m / 90, gw = m % 90;
                out[(size_t)ch * 1036800 + (size_t)(gh * 16 + ph) * 1440 + gw * 16 + pw] =
                    acc[i][j][r];
            }
        }
    }
}

// ---------------- fp32 DFT-stage GEMM: out = T[M,Kp] * D[Kp,N] ----------------
__global__ __launch_bounds__(256) void dft_gemm(const float* __restrict__ T,
                                                const float* __restrict__ D,
                                                float* __restrict__ outA,
                                                float* __restrict__ outB,
                                                int M, int N, int Kp, int ldD,
                                                int scatter, int ldOut) {
    __shared__ float Ts[16][68];
    __shared__ float Ds[16][132];
    int tid = threadIdx.x;
    int tx = tid & 15, ty = tid >> 4;
    int m0 = blockIdx.x * 64, n0 = blockIdx.y * 128;
    int lr = tid >> 2, lq = tid & 3;
    int dr = tid >> 4, dc = tid & 15;
    float acc[4][8] = {};
    for (int k0 = 0; k0 < Kp; k0 += 16) {
        int mr = m0 + lr; mr = mr < M ? mr : M - 1;
        float4 tv = *(const float4*)(T + (size_t)mr * Kp + k0 + lq * 4);
        Ts[lq * 4 + 0][lr] = tv.x;
        Ts[lq * 4 + 1][lr] = tv.y;
        Ts[lq * 4 + 2][lr] = tv.z;
        Ts[lq * 4 + 3][lr] = tv.w;
        const float* dp = D + (size_t)(k0 + dr) * ldD + n0 + dc * 4;
        float4 d0 = *(const float4*)dp;
        float4 d1 = *(const float4*)(dp + 64);
        Ds[dr][dc * 4 + 0] = d0.x; Ds[dr][dc * 4 + 1] = d0.y;
        Ds[dr][dc * 4 + 2] = d0.z; Ds[dr][dc * 4 + 3] = d0.w;
        Ds[dr][dc * 4 + 64] = d1.x; Ds[dr][dc * 4 + 65] = d1.y;
        Ds[dr][dc * 4 + 66] = d1.z; Ds[dr][dc * 4 + 67] = d1.w;
        __syncthreads();
#pragma unroll
        for (int kk = 0; kk < 16; kk++) {
            float a_[4], b_[8];
#pragma unroll
            for (int i = 0; i < 4; i++) a_[i] = Ts[kk][ty + 16 * i];
#pragma unroll
            for (int j = 0; j < 8; j++) b_[j] = Ds[kk][tx + 16 * j];
#pragma unroll
            for (int i = 0; i < 4; i++)
#pragma unroll
                for (int j = 0; j < 8; j++) acc[i][j] += a_[i] * b_[j];
        }
        __syncthreads();
    }
    int SP = M >> 1;
#pragma unroll
    for (int j = 0; j < 8; j++) {
        int n = n0 + tx + 16 * j;
        if (n >= N) continue;
        int h = n / 385, kk = n - h * 385;
#pragma unroll
        for (int i = 0; i < 4; i++) {
            int m = m0 + ty + 16 * i;
            if (m >= M) continue;
            int plane = m >= SP;
            int mp = plane ? m - SP : m;
            float* base = plane ? outB : outA;
            size_t g = scatter ? ((size_t)h * ldOut + (size_t)mp * 385 + kk)
                               : ((size_t)mp * ldOut + n);
            base[g] = acc[i][j];
        }
    }
}

// ---------------- build X = [a | n] per block (bf16) ----------------
__global__ __launch_bounds__(256) void build_an(const float* __restrict__ F3re,
                                                const float* __restrict__ F3im,
                                                const float* __restrict__ tln,
                                                u16* __restrict__ X) {
    int idx = blockIdx.x * 256 + threadIdx.x;
    if (idx >= NROW * 768) return;
    int c = idx % 768;
    int r = idx / 768;
    int h = r / KW, w0 = r % KW;
    int h2 = (45 - h) % 45, w2 = (90 - w0) % 90;
    float av;
    if (c <= 384) {
        size_t g = ((size_t)(h * 45 + w0)) * 385 + c;
        av = F3re[g] + F3im[g];
    } else {
        int k = 768 - c;
        int j2 = (w2 == 0) ? 0 : (w2 - 45);
        size_t g = ((size_t)(h2 * 45 + j2)) * 385 + k;
        av = F3re[g] - F3im[g];
    }
    float nv = tln[((size_t)(h2 * 90 + w2)) * 768 + c];
    int b = c / 96, o = c % 96;
    X[(size_t)r * 1536 + b * 192 + o] = f2b(av);
    X[(size_t)r * 1536 + b * 192 + 96 + o] = f2b(nv);
}

// ---------------- fused 3-stage block MLP (MFMA) ----------------
__global__ __launch_bounds__(256) void blk_fused(const u16* __restrict__ X,
                                                 const u16* __restrict__ WB1k,
                                                 const u16* __restrict__ WB1n,
                                                 const u16* __restrict__ WB2,
                                                 const u16* __restrict__ WB2s,
                                                 const float* __restrict__ b1l,
                                                 const float* __restrict__ b2l,
                                                 u16* __restrict__ ybuf16) {
    __shared__ u16 Ybuf[4][16 * 200];
    int b = blockIdx.x;
    int m0 = blockIdx.y * 64;
    int tid = threadIdx.x, lane = tid & 63, wave = tid >> 6;
    int lm = lane & 15, quad = lane >> 4;
    u16* Yw = &Ybuf[wave][0];

    int row = m0 + wave * 16 + lm;
    int rowc = row < NROW ? row : NROW - 1;
    const u16* Ab = X + (size_t)rowc * 1536 + b * 192;
    const u16* W1k = WB1k + (size_t)b * 18432;
    const u16* W1n = WB1n + (size_t)b * 18432;
    const u16* V2 = WB2 + (size_t)b * 18432;
    const u16* V2s = WB2s + (size_t)b * 18432;

    floatx4 z = {0.f, 0.f, 0.f, 0.f};
    floatx4 acc1[6], acc2[6];
#pragma unroll
    for (int j = 0; j < 6; j++) { acc1[j] = z; acc2[j] = z; }
    bf16x8 a[6];
#pragma unroll
    for (int k = 0; k < 6; k++) a[k] = *(const bf16x8*)(Ab + k * 32 + quad * 8);
#pragma unroll
    for (int k = 0; k < 6; k++)
#pragma unroll
        for (int j = 0; j < 6; j++) {
            bf16x8 w1 = *(const bf16x8*)(W1k + (size_t)(j * 16 + lm) * 192 + k * 32 + quad * 8);
            acc1[j] = __builtin_amdgcn_mfma_f32_16x16x32_bf16(a[k], w1, acc1[j], 0, 0, 0);
            bf16x8 w2 = *(const bf16x8*)(W1n + (size_t)(j * 16 + lm) * 192 + k * 32 + quad * 8);
            acc2[j] = __builtin_amdgcn_mfma_f32_16x16x32_bf16(a[k], w2, acc2[j], 0, 0, 0);
        }
    // stage1 epilogue -> Yw = [o1k | o1n]
#pragma unroll
    for (int j = 0; j < 6; j++) {
        int n = j * 16 + lm;
        float bA = b1l[b * 96 + n], bB = b1l[768 + b * 96 + n];
#pragma unroll
        for (int r = 0; r < 4; r++) {
            int mloc = quad * 4 + r;
            Yw[mloc * 200 + n] = f2b(fmaxf(acc1[j][r] + bA, 0.f));
            Yw[mloc * 200 + 96 + n] = f2b(fmaxf(acc2[j][r] + bB, 0.f));
        }
    }
    // stage2: o2k = [o1k|o1n]*[Vp|Vm] + b2k
    floatx4 acc3[6];
#pragma unroll
    for (int j = 0; j < 6; j++) acc3[j] = z;
    bf16x8 a2[6];
#pragma unroll
    for (int k = 0; k < 6; k++) a2[k] = *(const bf16x8*)(Yw + lm * 200 + k * 32 + quad * 8);
#pragma unroll
    for (int k = 0; k < 6; k++)
#pragma unroll
        for (int j = 0; j < 6; j++) {
            bf16x8 w = *(const bf16x8*)(V2 + (size_t)(j * 16 + lm) * 192 + k * 32 + quad * 8);
            acc3[j] = __builtin_amdgcn_mfma_f32_16x16x32_bf16(a2[k], w, acc3[j], 0, 0, 0);
        }
    float o2k[6][4];
#pragma unroll
    for (int j = 0; j < 6; j++) {
        int n = j * 16 + lm;
        float bA = b2l[b * 96 + n];
#pragma unroll
        for (int r = 0; r < 4; r++) {
            int mloc = quad * 4 + r;
            float v = acc3[j][r] + bA;
            o2k[j][r] = v;
            Yw[mloc * 200 + n] = f2b(v);  // Yw becomes [o2k | o1n]
        }
    }
    // stage3: o2n = [o2k|o1n]*[Vm|Vp] + b2n ; full = o2n + o2k ; soft-threshold
    floatx4 acc4[6];
#pragma unroll
    for (int j = 0; j < 6; j++) acc4[j] = z;
    bf16x8 a3[6];
#pragma unroll
    for (int k = 0; k < 6; k++) a3[k] = *(const bf16x8*)(Yw + lm * 200 + k * 32 + quad * 8);
#pragma unroll
    for (int k = 0; k < 6; k++)
#pragma unroll
        for (int j = 0; j < 6; j++) {
            bf16x8 w = *(const bf16x8*)(V2s + (size_t)(j * 16 + lm) * 192 + k * 32 + quad * 8);
            acc4[j] = __builtin_amdgcn_mfma_f32_16x16x32_bf16(a3[k], w, acc4[j], 0, 0, 0);
        }
#pragma unroll
    for (int j = 0; j < 6; j++) {
        int n = j * 16 + lm;
        float bB = b2l[768 + b * 96 + n];
#pragma unroll
        for (int r = 0; r < 4; r++) {
            int m = m0 + wave * 16 + quad * 4 + r;
            if (m >= NROW) continue;
            float full = acc4[j][r] + bB + o2k[j][r];
            float v = (full > LAMF) ? (full - LAMF) : ((full < -LAMF) ? (full + LAMF) : 0.f);
            ybuf16[(size_t)m * 768 + b * 96 + n] = f2b(v);
        }
    }
}

// ---------------- host ----------------
extern "C" void kernel_launch(void* const* d_in, const int* in_sizes, int n_in,
                              void* d_out, int out_size, void* d_ws, size_t ws_size,
                              hipStream_t stream) {
    const float* x       = (const float*)d_in[0];
    const float* patch_w = (const float*)d_in[1];
    const float* patch_b = (const float*)d_in[2];
    const float* pos     = (const float*)d_in[3];
    const float* n1w     = (const float*)d_in[4];
    const float* n1b     = (const float*)d_in[5];
    const float* w1      = (const float*)d_in[6];
    const float* b1      = (const float*)d_in[7];
    const float* w2      = (const float*)d_in[8];
    const float* b2      = (const float*)d_in[9];
    const float* n2w     = (const float*)d_in[10];
    const float* n2b     = (const float*)d_in[11];
    const float* fc1w    = (const float*)d_in[12];
    const float* fc1b    = (const float*)d_in[13];
    const float* fc2w    = (const float*)d_in[14];
    const float* fc2b    = (const float*)d_in[15];
    const float* headw   = (const float*)d_in[16];
    float* out = (float*)d_out;
    float* wsp = (float*)d_ws;

    size_t off = 0;
    auto af_ = [&](size_t n) { float* p = wsp + off; off += (n + 3) & ~(size_t)3; return p; };
    auto au_ = [&](size_t n) { u16* p = (u16*)(wsp + off); off += ((n + 1) / 2 + 3) & ~(size_t)3; return p; };

    u16* TCcs = au_(770 * 768);
    float* T_W1 = af_(90 * 192);
    float* T_H  = af_(90 * 96);
    float* T_W2 = af_(180 * 48);
    u16* WB1k = au_(147456);
    u16* WB1n = au_(147456);
    u16* WB2  = au_(147456);
    u16* WB2s = au_(147456);
    u16* fc1w16 = au_(2359296);
    u16* fc2w16 = au_(2359296);
    float* cur = af_(3110400);
    float* mid = af_(3110400);
    float* tlnA = af_(3110400);
    u16* tlnA16 = au_(3110400);
    u16* tlnB16 = au_(3110400);
    u16* Xb = au_(1589760);
    u16* ybuf16 = au_(794880);
    float* F3re = af_(1559250);
    float* F3im = af_(1559250);
    float* F4re = af_(1559250);
    float* F4im = af_(1559250);
    float* SCR = af_(10368000);  // holds patchA16 (20.74M u16) in patch phase
    // DFT scratch inside SCR
    float* D1 = SCR;                         // [192][LD1]   (90 xr + 90 xi + pad)
    float* D2 = D1 + (size_t)192 * LD1;      // [96][LD1]    (45 xr + 45 xi + pad)
    float* D3 = D2 + (size_t)96 * LD1;       // [48][LD1]    (23 xr + 23 xi + pad)
    float* D4 = D3 + (size_t)48 * LD1;       // [96][LD4]    (45 xr + 45 xi + pad)
    u16* hidden16 = (u16*)SCR;               // 12.44M u16 = 6.22M f (MLP phase)
    u16* patchA16 = (u16*)SCR;               // patch phase: gathered A [4050][5120] bf16
    u16* pw16 = fc1w16;                      // patch phase: patch weights (spans fc1w16+fc2w16)
    u16* Chi = (u16*)SCR;                    // head phase
    u16* Clo = Chi + 3110400;
    u16* Hhi = Clo + 3110400;
    u16* Hlo = Hhi + 3932160;
    size_t need = off * sizeof(float);
    if (ws_size < need) return;

    init_tables<<<2310, 256, 0, stream>>>(TCcs, T_W1, T_H, T_W2);

    // ---- patch embed: gather image -> bf16 A, then pipelined MFMA GEMM ----
    cast_f2b<<<3840, 256, 0, stream>>>(patch_w, pw16, 3932160);
    patch_gather<<<10125, 256, 0, stream>>>(x, patchA16);
    gemm_bf16<<<dim3(32, 6), 256, 0, stream>>>(patchA16, pw16, patch_b, pos, cur,
                                               NTOK, 768, 5120, 768, 2, 0, 0);

    for (int l = 0; l < 12; l++) {
        const float* w1l = w1 + (size_t)l * 147456;
        const float* b1l = b1 + (size_t)l * 1536;
        const float* w2l = w2 + (size_t)l * 147456;
        const float* b2l = b2 + (size_t)l * 1536;

        cast2_f2b<<<4608, 256, 0, stream>>>(fc1w + (size_t)l * 2359296,
                                            fc2w + (size_t)l * 2359296,
                                            fc1w16, fc2w16, 2359296);
        wpm_prep<<<576, 256, 0, stream>>>(w1l, w2l, WB1k, WB1n, WB2, WB2s);
        ln_kernel<<<NTOK, 256, 0, stream>>>(cur, n1w + l * 768, n1b + l * 768, tlnA, tlnA16);

        // DHT1: C-axis DFT (merged cos|sin) -> D1 [w][h][k] re plane + im plane
        gemm_bf16<<<dim3(32, 7), 256, 0, stream>>>(tlnA16, TCcs, nullptr, nullptr, D1,
                                                   NTOK, 770, 768, 90 * LD1, 3, 90, LD1);
        // W-axis (90 -> 45 selected) -> D2 [h][j][k]
        dft_gemm<<<dim3(2, 136), 256, 0, stream>>>(T_W1, D1, D2, D2 + (size_t)45 * LD1,
                                                   90, 17325, 192, LD1, 1, LD1);
        // H-axis (45 -> 45) -> F3 planes [i][j][k]
        dft_gemm<<<dim3(2, 136), 256, 0, stream>>>(T_H, D2, F3re, F3im,
                                                   90, 17325, 96, LD1, 0, 17325);
        build_an<<<(NROW * 768 + 255) / 256, 256, 0, stream>>>(F3re, F3im, tlnA, Xb);

        // fused block MLP
        blk_fused<<<dim3(8, 17), 256, 0, stream>>>(Xb, WB1k, WB1n, WB2, WB2s,
                                                   b1l, b2l, ybuf16);

        // DHT2: C-axis DFT (merged) -> D3 [w0][h][k] re + im planes
        gemm_bf16<<<dim3(9, 7), 256, 0, stream>>>(ybuf16, TCcs, nullptr, nullptr, D3,
                                                  NROW, 770, 768, 23 * LD1, 3, 23, LD1);
        // W-axis (23 -> 90) -> D4 [h][j][k]
        dft_gemm<<<dim3(3, 136), 256, 0, stream>>>(T_W2, D3, D4, D4 + (size_t)45 * LD4,
                                                   180, 17325, 48, LD1, 1, LD4);
        // H-axis (45 -> 45) -> F4 planes [i][j][k]
        dft_gemm<<<dim3(2, 271), 256, 0, stream>>>(T_H, D4, F4re, F4im,
                                                   90, 34650, 96, LD4, 0, 34650);
        // combine + LN2 fused
        ln2c_kernel<<<NTOK, 256, 0, stream>>>(F4re, F4im, cur, tlnA,
                                              n2w + l * 768, n2b + l * 768, mid, tlnB16);

        // MLP
        gemm_bf16<<<dim3(32, 24), 256, 0, stream>>>(tlnB16, fc1w16, fc1b + l * 3072, nullptr,
                                                    hidden16, NTOK, 3072, 768, 3072, 1, 0, 0);
        gemm_bf16<<<dim3(32, 6), 256, 0, stream>>>(hidden16, fc2w16, fc2b + l * 768, mid,
                                                   cur, NTOK, 768, 3072, 768, 2, 0, 0);
    }

    // ---- head: split-bf16 GEMM (permuted B rows) + coalesced scatter ----
    cast_split<<<3038, 256, 0, stream>>>(cur, Chi, Clo, 3110400);
    cast_split_perm<<<3840, 256, 0, stream>>>(headw, Hhi, Hlo);
    gemm_split<<<dim3(32, 40), 256, 0, stream>>>(Chi, Clo, Hhi, Hlo, out,
                                                 NTOK, 5120, 768);
}

// Round 3
// 4292.571 us; speedup vs baseline: 1.4441x; 1.0888x over previous
//
#include <hip/hip_runtime.h>
#include <math.h>

typedef __attribute__((ext_vector_type(4))) float floatx4;
typedef __attribute__((ext_vector_type(8))) short bf16x8;
typedef unsigned short u16;

#define NTOK 4050
#define KW 23
#define NROW 1035
#define SZ_ALL 3110400.0f
#define LAMF 0.01f
#define LD1 17344   // padded row length for D1/D2/D3 (>=17325, mult of 64)
#define LD4 34688   // padded row length for D4 (>=34650, mult of 64)

#define GLP(p) ((const __attribute__((address_space(1))) void*)(p))
#define LDSP(p) ((__attribute__((address_space(3))) void*)(p))

__device__ __forceinline__ u16 f2b(float f) {
    union { float f; unsigned int u; } x;
    x.f = f;
    unsigned int r = x.u + 0x7FFFu + ((x.u >> 16) & 1u);
    return (u16)(r >> 16);
}
__device__ __forceinline__ float b2f(u16 u) {
    union { unsigned int u; float f; } x;
    x.u = ((unsigned int)u) << 16;
    return x.f;
}

// ---------------- LN (norm1): fp32 out + bf16 out ----------------
__global__ __launch_bounds__(256) void ln_kernel(const float* __restrict__ x,
                                                 const float* __restrict__ w,
                                                 const float* __restrict__ b,
                                                 float* __restrict__ y,
                                                 u16* __restrict__ y16) {
    __shared__ float red[256];
    int t = blockIdx.x;
    int tid = threadIdx.x;
    const float* row = x + (size_t)t * 768;
    float v0 = row[tid], v1 = row[tid + 256], v2 = row[tid + 512];
    red[tid] = v0 + v1 + v2;
    __syncthreads();
    for (int off = 128; off > 0; off >>= 1) {
        if (tid < off) red[tid] += red[tid + off];
        __syncthreads();
    }
    float mean = red[0] * (1.0f / 768.0f);
    __syncthreads();
    float d0 = v0 - mean, d1 = v1 - mean, d2 = v2 - mean;
    red[tid] = d0 * d0 + d1 * d1 + d2 * d2;
    __syncthreads();
    for (int off = 128; off > 0; off >>= 1) {
        if (tid < off) red[tid] += red[tid + off];
        __syncthreads();
    }
    float rstd = rsqrtf(red[0] * (1.0f / 768.0f) + 1e-5f);
    float* yr = y + (size_t)t * 768;
    u16* ys = y16 + (size_t)t * 768;
    float o0 = d0 * rstd * w[tid] + b[tid];
    float o1 = d1 * rstd * w[tid + 256] + b[tid + 256];
    float o2 = d2 * rstd * w[tid + 512] + b[tid + 512];
    yr[tid] = o0; yr[tid + 256] = o1; yr[tid + 512] = o2;
    ys[tid] = f2b(o0); ys[tid + 256] = f2b(o1); ys[tid + 512] = f2b(o2);
}

// ---------------- fused afno-combine + LN (norm2) ----------------
__global__ __launch_bounds__(256) void ln2c_kernel(const float* __restrict__ F4re,
                                                   const float* __restrict__ F4im,
                                                   const float* __restrict__ cur,
                                                   const float* __restrict__ tlnA,
                                                   const float* __restrict__ w,
                                                   const float* __restrict__ b,
                                                   float* __restrict__ mid,
                                                   u16* __restrict__ y16) {
    __shared__ float red[256];
    int t = blockIdx.x;
    int tid = threadIdx.x;
    int h = t / 90, w0 = t % 90;
    int h2 = (45 - h) % 45, w2 = (90 - w0) % 90;
    float vv[3];
#pragma unroll
    for (int s = 0; s < 3; s++) {
        int c = tid + s * 256;
        float v;
        if (c <= 384) {
            size_t g = (size_t)h * 34650 + (size_t)w0 * 385 + c;
            v = F4re[g] + F4im[g];
        } else {
            int k = 768 - c;
            size_t g = (size_t)h2 * 34650 + (size_t)w2 * 385 + k;
            v = F4re[g] - F4im[g];
        }
        size_t gi = (size_t)t * 768 + c;
        v = cur[gi] + tlnA[gi] + v * (1.0f / SZ_ALL);
        mid[gi] = v;
        vv[s] = v;
    }
    red[tid] = vv[0] + vv[1] + vv[2];
    __syncthreads();
    for (int off = 128; off > 0; off >>= 1) {
        if (tid < off) red[tid] += red[tid + off];
        __syncthreads();
    }
    float mean = red[0] * (1.0f / 768.0f);
    __syncthreads();
    float d0 = vv[0] - mean, d1 = vv[1] - mean, d2 = vv[2] - mean;
    red[tid] = d0 * d0 + d1 * d1 + d2 * d2;
    __syncthreads();
    for (int off = 128; off > 0; off >>= 1) {
        if (tid < off) red[tid] += red[tid + off];
        __syncthreads();
    }
    float rstd = rsqrtf(red[0] * (1.0f / 768.0f) + 1e-5f);
    u16* ys = y16 + (size_t)t * 768;
    ys[tid]       = f2b(d0 * rstd * w[tid] + b[tid]);
    ys[tid + 256] = f2b(d1 * rstd * w[tid + 256] + b[tid + 256]);
    ys[tid + 512] = f2b(d2 * rstd * w[tid + 512] + b[tid + 512]);
}

// ---------------- tables ----------------
// TCcs: stacked [770][768]; rows 0..384 = cos table, rows 385..769 = -sin table
__global__ __launch_bounds__(256) void init_tables(u16* TCcs, float* T_W1,
                                                   float* T_H, float* T_W2) {
    int gid = blockIdx.x * 256 + threadIdx.x;
    const double TP = 6.283185307179586476925286766559;
    if (gid < 770 * 768) {
        int n = gid / 768, c = gid % 768;
        int f = n < 385 ? n : n - 385;
        int r = (f * c) % 768;
        double a = TP * (double)r / 768.0;
        TCcs[gid] = f2b(n < 385 ? (float)cos(a) : (float)(-sin(a)));
    }
    if (gid < 90 * 192) {  // T_W1 [90][192]
        int m = gid / 192, kp = gid % 192;
        int j = m % 45, im = m / 45;
        int jf = j < 23 ? j : j + 45;
        float val = 0.f;
        if (kp < 90) {
            double a = TP * (double)((jf * kp) % 90) / 90.0;
            val = im ? (float)(-sin(a)) : (float)cos(a);
        } else if (kp < 180) {
            int ww = kp - 90;
            double a = TP * (double)((jf * ww) % 90) / 90.0;
            val = im ? (float)cos(a) : (float)sin(a);
        }
        T_W1[gid] = val;
    }
    if (gid < 90 * 96) {  // T_H [90][96]
        int m = gid / 96, kp = gid % 96;
        int i = m % 45, im = m / 45;
        float val = 0.f;
        if (kp < 45) {
            double a = TP * (double)((i * kp) % 45) / 45.0;
            val = im ? (float)(-sin(a)) : (float)cos(a);
        } else if (kp < 90) {
            int hh = kp - 45;
            double a = TP * (double)((i * hh) % 45) / 45.0;
            val = im ? (float)cos(a) : (float)sin(a);
        }
        T_H[gid] = val;
    }
    if (gid < 180 * 48) {  // T_W2 [180][48]
        int m = gid / 48, kp = gid % 48;
        int j = m % 90, im = m / 90;
        float val = 0.f;
        if (kp < 23) {
            double a = TP * (double)((j * kp) % 90) / 90.0;
            val = im ? (float)(-sin(a)) : (float)cos(a);
        } else if (kp < 46) {
            int ww = kp - 23;
            double a = TP * (double)((j * ww) % 90) / 90.0;
            val = im ? (float)cos(a) : (float)sin(a);
        }
        T_W2[gid] = val;
    }
}

// ---------------- casts ----------------
__global__ __launch_bounds__(256) void cast_f2b(const float* __restrict__ in,
                                                u16* __restrict__ out, int n) {
    int i = (blockIdx.x * 256 + threadIdx.x) * 4;
    if (i >= n) return;
    float4 v = *(const float4*)(in + i);
    out[i] = f2b(v.x); out[i + 1] = f2b(v.y); out[i + 2] = f2b(v.z); out[i + 3] = f2b(v.w);
}

// two independent casts fused in one dispatch (saves launches per layer)
__global__ __launch_bounds__(256) void cast2_f2b(const float* __restrict__ in1,
                                                 const float* __restrict__ in2,
                                                 u16* __restrict__ out1,
                                                 u16* __restrict__ out2, int n) {
    int i = (blockIdx.x * 256 + threadIdx.x) * 4;
    const float* in = in1;
    u16* out = out1;
    if (i >= n) { in = in2; out = out2; i -= n; }
    if (i >= n) return;
    float4 v = *(const float4*)(in + i);
    out[i] = f2b(v.x); out[i + 1] = f2b(v.y); out[i + 2] = f2b(v.z); out[i + 3] = f2b(v.w);
}

__global__ __launch_bounds__(256) void cast_split(const float* __restrict__ in,
                                                  u16* __restrict__ hi,
                                                  u16* __restrict__ lo, int n) {
    int i = (blockIdx.x * 256 + threadIdx.x) * 4;
    if (i >= n) return;
    float4 v = *(const float4*)(in + i);
    float vs[4] = {v.x, v.y, v.z, v.w};
#pragma unroll
    for (int s = 0; s < 4; s++) {
        u16 h = f2b(vs[s]);
        hi[i + s] = h;
        lo[i + s] = f2b(vs[s] - b2f(h));
    }
}

// head weights: split + row permutation  o=ph*320+pw*20+ch -> o'=ch*256+ph*16+pw
__global__ __launch_bounds__(256) void cast_split_perm(const float* __restrict__ in,
                                                       u16* __restrict__ hi,
                                                       u16* __restrict__ lo) {
    int i = (blockIdx.x * 256 + threadIdx.x) * 4;
    if (i >= 3932160) return;
    int o = i / 768, c = i % 768;
    int ch = o % 20, qq = o / 20;
    int pw = qq & 15, ph = qq >> 4;
    size_t dst = (size_t)(ch * 256 + ph * 16 + pw) * 768 + c;
    float4 v = *(const float4*)(in + i);
    float vs[4] = {v.x, v.y, v.z, v.w};
#pragma unroll
    for (int s = 0; s < 4; s++) {
        u16 h = f2b(vs[s]);
        hi[dst + s] = h;
        lo[dst + s] = f2b(vs[s] - b2f(h));
    }
}

// ---------------- patch gather: image -> bf16 A [NTOK][5120] ----------------
__global__ __launch_bounds__(256) void patch_gather(const float* __restrict__ img,
                                                    u16* __restrict__ A16) {
    int gid = blockIdx.x * 256 + threadIdx.x;  // one thread per 8 elems
    if (gid >= NTOK * 640) return;
    int t = gid / 640;
    int k8 = (gid - t * 640) * 8;
    int gh = t / 90, gw = t - gh * 90;
    int c = k8 >> 8, ph = (k8 >> 4) & 15, pw = k8 & 15;
    const float* p = img + (size_t)c * 1036800 + (size_t)(gh * 16 + ph) * 1440 + gw * 16 + pw;
    float4 u0 = *(const float4*)p;
    float4 u1 = *(const float4*)(p + 4);
    union { bf16x8 v; u16 s[8]; } o;
    o.s[0] = f2b(u0.x); o.s[1] = f2b(u0.y); o.s[2] = f2b(u0.z); o.s[3] = f2b(u0.w);
    o.s[4] = f2b(u1.x); o.s[5] = f2b(u1.y); o.s[6] = f2b(u1.z); o.s[7] = f2b(u1.w);
    *(bf16x8*)(A16 + (size_t)t * 5120 + k8) = o.v;
}

// ---------------- packed block-MLP weights ----------------
__global__ __launch_bounds__(256) void wpm_prep(const float* __restrict__ w1l,
                                                const float* __restrict__ w2l,
                                                u16* WB1k, u16* WB1n, u16* WB2, u16* WB2s) {
    int i = blockIdx.x * 256 + threadIdx.x;
    if (i >= 147456) return;
    int ii = i % 192;
    int o = (i / 192) % 96;
    int b = i / (192 * 96);
    int si = ii < 96 ? ii : ii - 96;
    size_t base = (size_t)b * 9216 + si * 96 + o;
    float p0 = w1l[base], p1 = w1l[73728 + base];
    float wp = 0.5f * (p0 + p1), wm = 0.5f * (p0 - p1);
    float q0 = w2l[base], q1 = w2l[73728 + base];
    float vp = 0.5f * (q0 + q1), vm = 0.5f * (q0 - q1);
    WB1k[i] = f2b(ii < 96 ? wp : wm);
    WB1n[i] = f2b(ii < 96 ? wm : wp);
    WB2[i] = f2b(ii < 96 ? vp : vm);
    WB2s[i] = f2b(ii < 96 ? vm : vp);
}

// ---------------- bf16 MFMA GEMM: out = A[M,K] * B[N,K]^T ----------------
// 64x128 tile, 4 waves (wave-tile 32x64), 4-deep pipeline w/ counted vmcnt.
// LDS XOR-swizzle via pre-swizzled global source (dest linear, rule #21).
// emode 0: fp32 direct; 1: bf16 gelu(acc+bias); 2: fp32 acc+bias+extra;
// emode 3: fp32 scatter, merged cos/sin planes (ldout = plane offset)
__global__ __launch_bounds__(256) void gemm_bf16(const u16* __restrict__ A,
                                                 const u16* __restrict__ B,
                                                 const float* __restrict__ bias,
                                                 const float* __restrict__ extra,
                                                 void* __restrict__ out,
                                                 int M, int N, int K, int ldout,
                                                 int emode, int q, int ldd) {
    __shared__ u16 As[4][2048];   // 64 rows x 32
    __shared__ u16 Bs[4][4096];   // 128 rows x 32
    int tid = threadIdx.x;
    int m0 = blockIdx.x * 64, n0 = blockIdx.y * 128;
    int srow = tid >> 2;
    int sk8 = (((tid & 3) ^ (srow & 3))) * 8;   // pre-swizzled source chunk
    int ar0 = m0 + srow;        ar0 = ar0 < M ? ar0 : M - 1;
    const u16* Ag0 = A + (size_t)ar0 * K + sk8;
    int br0 = n0 + srow;        br0 = br0 < N ? br0 : N - 1;
    int br1 = n0 + 64 + srow;   br1 = br1 < N ? br1 : N - 1;
    const u16* Bg0 = B + (size_t)br0 * K + sk8;
    const u16* Bg1 = B + (size_t)br1 * K + sk8;

    int lane = tid & 63, wave = tid >> 6;
    int wm = (wave & 1) * 32, wn = (wave >> 1) * 64;
    int lm = lane & 15, quad = lane >> 4;
    int swr = (quad ^ (lm & 3)) * 8;            // swizzled read slot

    floatx4 acc[2][4];
    floatx4 z = {0.f, 0.f, 0.f, 0.f};
#pragma unroll
    for (int i = 0; i < 2; i++)
#pragma unroll
        for (int j = 0; j < 4; j++) acc[i][j] = z;

#define GSTAGE(tt, bb) do { int k0_ = (tt) * 32;                                             \
    __builtin_amdgcn_global_load_lds(GLP(Ag0 + k0_), LDSP(&As[bb][tid * 8]), 16, 0, 0);      \
    __builtin_amdgcn_global_load_lds(GLP(Bg0 + k0_), LDSP(&Bs[bb][tid * 8]), 16, 0, 0);      \
    __builtin_amdgcn_global_load_lds(GLP(Bg1 + k0_), LDSP(&Bs[bb][2048 + tid * 8]), 16, 0, 0);} while (0)

    int nt = K >> 5;
    GSTAGE(0, 0);
    if (nt > 1) GSTAGE(1, 1);
    if (nt > 2) GSTAGE(2, 2);
    if (nt > 3) GSTAGE(3, 3);
    int buf = 0;
    for (int t = 0; t < nt; t++) {
        int rem = nt - 1 - t;  // tiles beyond t
        if (rem >= 3)      asm volatile("s_waitcnt vmcnt(9)" ::: "memory");
        else if (rem == 2) asm volatile("s_waitcnt vmcnt(6)" ::: "memory");
        else if (rem == 1) asm volatile("s_waitcnt vmcnt(3)" ::: "memory");
        else               asm volatile("s_waitcnt vmcnt(0)" ::: "memory");
        asm volatile("s_barrier" ::: "memory");
        bf16x8 af[2], bfr[4];
#pragma unroll
        for (int i = 0; i < 2; i++)
            af[i] = *(const bf16x8*)&As[buf][(wm + i * 16 + lm) * 32 + swr];
#pragma unroll
        for (int j = 0; j < 4; j++)
            bfr[j] = *(const bf16x8*)&Bs[buf][(wn + j * 16 + lm) * 32 + swr];
#pragma unroll
        for (int i = 0; i < 2; i++)
#pragma unroll
            for (int j = 0; j < 4; j++)
                acc[i][j] = __builtin_amdgcn_mfma_f32_16x16x32_bf16(af[i], bfr[j], acc[i][j], 0, 0, 0);
        asm volatile("s_barrier" ::: "memory");
        if (t + 4 < nt) GSTAGE(t + 4, buf);
        buf = (buf + 1) & 3;
    }
#undef GSTAGE

#pragma unroll
    for (int j = 0; j < 4; j++) {
        int n = n0 + wn + j * 16 + lm;
        if (n >= N) continue;
        float bn = (emode == 1 || emode == 2) ? bias[n] : 0.f;
#pragma unroll
        for (int i = 0; i < 2; i++) {
#pragma unroll
            for (int r = 0; r < 4; r++) {
                int m = m0 + wm + i * 16 + quad * 4 + r;
                if (m >= M) continue;
                float v = acc[i][j][r];
                if (emode == 0) {
                    ((float*)out)[(size_t)m * ldout + n] = v;
                } else if (emode == 1) {
                    v += bn;
                    float gl = 0.5f * v * (1.0f + erff(v * 0.70710678118654752f));
                    ((u16*)out)[(size_t)m * ldout + n] = f2b(gl);
                } else if (emode == 2) {
                    size_t g = (size_t)m * ldout + n;
                    ((float*)out)[g] = v + bn + extra[g];
                } else {
                    int plane = n >= 385;
                    int col = plane ? n - 385 : n;
                    size_t g = (size_t)(m % q) * ldd + (size_t)(m / q) * 385 + col
                             + (plane ? (size_t)ldout : (size_t)0);
                    ((float*)out)[g] = v;
                }
            }
        }
    }
}

// ---------------- split-bf16 GEMM (head) ----------------
__global__ __launch_bounds__(256) void gemm_split(const u16* __restrict__ Ahi,
                                                  const u16* __restrict__ Alo,
                                                  const u16* __restrict__ Bhi,
                                                  const u16* __restrict__ Blo,
                                                  float* __restrict__ out,
                                                  int M, int N, int K) {
    __shared__ u16 Ash[2][4096];
    __shared__ u16 Asl[2][4096];
    __shared__ u16 Bsh[2][4096];
    __shared__ u16 Bsl[2][4096];
    int tid = threadIdx.x;
    int m0 = blockIdx.x * 128, n0 = blockIdx.y * 128;
    int srow = tid >> 2;
    int sk8 = (((tid & 3) ^ (srow & 3))) * 8;
    int ar0 = m0 + srow;        ar0 = ar0 < M ? ar0 : M - 1;
    int ar1 = m0 + 64 + srow;   ar1 = ar1 < M ? ar1 : M - 1;
    int br0 = n0 + srow;        br0 = br0 < N ? br0 : N - 1;
    int br1 = n0 + 64 + srow;   br1 = br1 < N ? br1 : N - 1;
    size_t a0 = (size_t)ar0 * K + sk8, a1 = (size_t)ar1 * K + sk8;
    size_t b0 = (size_t)br0 * K + sk8, b1 = (size_t)br1 * K + sk8;

    int lane = tid & 63, wave = tid >> 6;
    int wm = (wave & 1) * 64, wn = (wave >> 1) * 64;
    int lm = lane & 15, quad = lane >> 4;
    int swr = (quad ^ (lm & 3)) * 8;

    floatx4 acc[4][4];
    floatx4 z = {0.f, 0.f, 0.f, 0.f};
#pragma unroll
    for (int i = 0; i < 4; i++)
#pragma unroll
        for (int j = 0; j < 4; j++) acc[i][j] = z;

#define SSTAGE(tt, bb) do { int k0_ = (tt) * 32;                                               \
    __builtin_amdgcn_global_load_lds(GLP(Ahi + a0 + k0_), LDSP(&Ash[bb][tid * 8]), 16, 0, 0);  \
    __builtin_amdgcn_global_load_lds(GLP(Ahi + a1 + k0_), LDSP(&Ash[bb][2048 + tid * 8]), 16, 0, 0);\
    __builtin_amdgcn_global_load_lds(GLP(Alo + a0 + k0_), LDSP(&Asl[bb][tid * 8]), 16, 0, 0);  \
    __builtin_amdgcn_global_load_lds(GLP(Alo + a1 + k0_), LDSP(&Asl[bb][2048 + tid * 8]), 16, 0, 0);\
    __builtin_amdgcn_global_load_lds(GLP(Bhi + b0 + k0_), LDSP(&Bsh[bb][tid * 8]), 16, 0, 0);  \
    __builtin_amdgcn_global_load_lds(GLP(Bhi + b1 + k0_), LDSP(&Bsh[bb][2048 + tid * 8]), 16, 0, 0);\
    __builtin_amdgcn_global_load_lds(GLP(Blo + b0 + k0_), LDSP(&Bsl[bb][tid * 8]), 16, 0, 0);  \
    __builtin_amdgcn_global_load_lds(GLP(Blo + b1 + k0_), LDSP(&Bsl[bb][2048 + tid * 8]), 16, 0, 0);} while (0)

    int nt = K >> 5;
    SSTAGE(0, 0);
    if (nt > 1) SSTAGE(1, 1);
    int buf = 0;
    for (int t = 0; t < nt; t++) {
        int rem = nt - 1 - t;
        if (rem >= 1) asm volatile("s_waitcnt vmcnt(8)" ::: "memory");
        else          asm volatile("s_waitcnt vmcnt(0)" ::: "memory");
        asm volatile("s_barrier" ::: "memory");
        bf16x8 ah[4], al[4], bh[4], bl[4];
#pragma unroll
        for (int i = 0; i < 4; i++) {
            ah[i] = *(const bf16x8*)&Ash[buf][(wm + i * 16 + lm) * 32 + swr];
            al[i] = *(const bf16x8*)&Asl[buf][(wm + i * 16 + lm) * 32 + swr];
        }
#pragma unroll
        for (int j = 0; j < 4; j++) {
            bh[j] = *(const bf16x8*)&Bsh[buf][(wn + j * 16 + lm) * 32 + swr];
            bl[j] = *(const bf16x8*)&Bsl[buf][(wn + j * 16 + lm) * 32 + swr];
        }
#pragma unroll
        for (int i = 0; i < 4; i++)
#pragma unroll
            for (int j = 0; j < 4; j++) {
                acc[i][j] = __builtin_amdgcn_mfma_f32_16x16x32_bf16(al[i], bh[j], acc[i][j], 0, 0, 0);
                acc[i][j] = __builtin_amdgcn_mfma_f32_16x16x32_bf16(ah[i], bl[j], acc[i][j], 0, 0, 0);
                acc[i][j] = __builtin_amdgcn_mfma_f32_16x16x32_bf16(ah[i], bh[j], acc[i][j], 0, 0, 0);
            }
        asm volatile("s_barrier" ::: "memory");
        if (t + 2 < nt) SSTAGE(t + 2, buf);
        buf ^= 1;
    }
#undef SSTAGE

#pragma unroll
    for (int j = 0; j < 4; j++) {
        int n = n0 + wn + j * 16 + lm;
        if (n >= N) continue;
        int ch = n >> 8;                  // permuted decode
        int ph = (n >> 4) & 15, pw = n & 15;
#pragma unroll
        for (int i = 0; i < 4; i++) {
#pragma unroll
            for (int r = 0; r < 4; r++) {
                int m = m0 + wm + i * 16 + quad * 4 + r;
                if (m >= M) continue;
                int gh = m / 90, gw = m % 90;
                out[(size_t)ch * 1036800 + (size_t)(gh * 16 + ph) * 1440 + gw * 16 + pw] =
                    acc[i][j][r];
            }
        }
    }
}

// ---------------- fp32 DFT-stage GEMM: out = T[M,Kp] * D[Kp,N] ----------------
__global__ __launch_bounds__(256) void dft_gemm(const float* __restrict__ T,
                                                const float* __restrict__ D,
                                                float* __restrict__ outA,
                                                float* __restrict__ outB,
                                                int M, int N, int Kp, int ldD,
                                                int scatter, int ldOut) {
    __shared__ float Ts[16][68];
    __shared__ float Ds[16][132];
    int tid = threadIdx.x;
    int tx = tid & 15, ty = tid >> 4;
    int m0 = blockIdx.x * 64, n0 = blockIdx.y * 128;
    int lr = tid >> 2, lq = tid & 3;
    int dr = tid >> 4, dc = tid & 15;
    float acc[4][8] = {};
    for (int k0 = 0; k0 < Kp; k0 += 16) {
        int mr = m0 + lr; mr = mr < M ? mr : M - 1;
        float4 tv = *(const float4*)(T + (size_t)mr * Kp + k0 + lq * 4);
        Ts[lq * 4 + 0][lr] = tv.x;
        Ts[lq * 4 + 1][lr] = tv.y;
        Ts[lq * 4 + 2][lr] = tv.z;
        Ts[lq * 4 + 3][lr] = tv.w;
        const float* dp = D + (size_t)(k0 + dr) * ldD + n0 + dc * 4;
        float4 d0 = *(const float4*)dp;
        float4 d1 = *(const float4*)(dp + 64);
        Ds[dr][dc * 4 + 0] = d0.x; Ds[dr][dc * 4 + 1] = d0.y;
        Ds[dr][dc * 4 + 2] = d0.z; Ds[dr][dc * 4 + 3] = d0.w;
        Ds[dr][dc * 4 + 64] = d1.x; Ds[dr][dc * 4 + 65] = d1.y;
        Ds[dr][dc * 4 + 66] = d1.z; Ds[dr][dc * 4 + 67] = d1.w;
        __syncthreads();
#pragma unroll
        for (int kk = 0; kk < 16; kk++) {
            float a_[4], b_[8];
#pragma unroll
            for (int i = 0; i < 4; i++) a_[i] = Ts[kk][ty + 16 * i];
#pragma unroll
            for (int j = 0; j < 8; j++) b_[j] = Ds[kk][tx + 16 * j];
#pragma unroll
            for (int i = 0; i < 4; i++)
#pragma unroll
                for (int j = 0; j < 8; j++) acc[i][j] += a_[i] * b_[j];
        }
        __syncthreads();
    }
    int SP = M >> 1;
#pragma unroll
    for (int j = 0; j < 8; j++) {
        int n = n0 + tx + 16 * j;
        if (n >= N) continue;
        int h = n / 385, kk = n - h * 385;
#pragma unroll
        for (int i = 0; i < 4; i++) {
            int m = m0 + ty + 16 * i;
            if (m >= M) continue;
            int plane = m >= SP;
            int mp = plane ? m - SP : m;
            float* base = plane ? outB : outA;
            size_t g = scatter ? ((size_t)h * ldOut + (size_t)mp * 385 + kk)
                               : ((size_t)mp * ldOut + n);
            base[g] = acc[i][j];
        }
    }
}

// ---------------- build X = [a | n] per block (bf16) ----------------
__global__ __launch_bounds__(256) void build_an(const float* __restrict__ F3re,
                                                const float* __restrict__ F3im,
                                                const float* __restrict__ tln,
                                                u16* __restrict__ X) {
    int idx = blockIdx.x * 256 + threadIdx.x;
    if (idx >= NROW * 768) return;
    int c = idx % 768;
    int r = idx / 768;
    int h = r / KW, w0 = r % KW;
    int h2 = (45 - h) % 45, w2 = (90 - w0) % 90;
    float av;
    if (c <= 384) {
        size_t g = ((size_t)(h * 45 + w0)) * 385 + c;
        av = F3re[g] + F3im[g];
    } else {
        int k = 768 - c;
        int j2 = (w2 == 0) ? 0 : (w2 - 45);
        size_t g = ((size_t)(h2 * 45 + j2)) * 385 + k;
        av = F3re[g] - F3im[g];
    }
    float nv = tln[((size_t)(h2 * 90 + w2)) * 768 + c];
    int b = c / 96, o = c % 96;
    X[(size_t)r * 1536 + b * 192 + o] = f2b(av);
    X[(size_t)r * 1536 + b * 192 + 96 + o] = f2b(nv);
}

// ---------------- fused 3-stage block MLP (MFMA), 2 waves/block ----------------
__global__ __launch_bounds__(128) void blk_fused(const u16* __restrict__ X,
                                                 const u16* __restrict__ WB1k,
                                                 const u16* __restrict__ WB1n,
                                                 const u16* __restrict__ WB2,
                                                 const u16* __restrict__ WB2s,
                                                 const float* __restrict__ b1l,
                                                 const float* __restrict__ b2l,
                                                 u16* __restrict__ ybuf16) {
    __shared__ u16 Ybuf[2][16 * 200];
    int b = blockIdx.x;
    int m0 = blockIdx.y * 32;
    int tid = threadIdx.x, lane = tid & 63, wave = tid >> 6;
    int lm = lane & 15, quad = lane >> 4;
    u16* Yw = &Ybuf[wave][0];

    int row = m0 + wave * 16 + lm;
    int rowc = row < NROW ? row : NROW - 1;
    const u16* Ab = X + (size_t)rowc * 1536 + b * 192;
    const u16* W1k = WB1k + (size_t)b * 18432;
    const u16* W1n = WB1n + (size_t)b * 18432;
    const u16* V2 = WB2 + (size_t)b * 18432;
    const u16* V2s = WB2s + (size_t)b * 18432;

    floatx4 z = {0.f, 0.f, 0.f, 0.f};
    floatx4 acc1[6], acc2[6];
#pragma unroll
    for (int j = 0; j < 6; j++) { acc1[j] = z; acc2[j] = z; }
    bf16x8 a[6];
#pragma unroll
    for (int k = 0; k < 6; k++) a[k] = *(const bf16x8*)(Ab + k * 32 + quad * 8);
#pragma unroll
    for (int k = 0; k < 6; k++)
#pragma unroll
        for (int j = 0; j < 6; j++) {
            bf16x8 w1 = *(const bf16x8*)(W1k + (size_t)(j * 16 + lm) * 192 + k * 32 + quad * 8);
            acc1[j] = __builtin_amdgcn_mfma_f32_16x16x32_bf16(a[k], w1, acc1[j], 0, 0, 0);
            bf16x8 w2 = *(const bf16x8*)(W1n + (size_t)(j * 16 + lm) * 192 + k * 32 + quad * 8);
            acc2[j] = __builtin_amdgcn_mfma_f32_16x16x32_bf16(a[k], w2, acc2[j], 0, 0, 0);
        }
    // stage1 epilogue -> Yw = [o1k | o1n]
#pragma unroll
    for (int j = 0; j < 6; j++) {
        int n = j * 16 + lm;
        float bA = b1l[b * 96 + n], bB = b1l[768 + b * 96 + n];
#pragma unroll
        for (int r = 0; r < 4; r++) {
            int mloc = quad * 4 + r;
            Yw[mloc * 200 + n] = f2b(fmaxf(acc1[j][r] + bA, 0.f));
            Yw[mloc * 200 + 96 + n] = f2b(fmaxf(acc2[j][r] + bB, 0.f));
        }
    }
    // stage2: o2k = [o1k|o1n]*[Vp|Vm] + b2k
    floatx4 acc3[6];
#pragma unroll
    for (int j = 0; j < 6; j++) acc3[j] = z;
    bf16x8 a2[6];
#pragma unroll
    for (int k = 0; k < 6; k++) a2[k] = *(const bf16x8*)(Yw + lm * 200 + k * 32 + quad * 8);
#pragma unroll
    for (int k = 0; k < 6; k++)
#pragma unroll
        for (int j = 0; j < 6; j++) {
            bf16x8 w = *(const bf16x8*)(V2 + (size_t)(j * 16 + lm) * 192 + k * 32 + quad * 8);
            acc3[j] = __builtin_amdgcn_mfma_f32_16x16x32_bf16(a2[k], w, acc3[j], 0, 0, 0);
        }
    float o2k[6][4];
#pragma unroll
    for (int j = 0; j < 6; j++) {
        int n = j * 16 + lm;
        float bA = b2l[b * 96 + n];
#pragma unroll
        for (int r = 0; r < 4; r++) {
            int mloc = quad * 4 + r;
            float v = acc3[j][r] + bA;
            o2k[j][r] = v;
            Yw[mloc * 200 + n] = f2b(v);  // Yw becomes [o2k | o1n]
        }
    }
    // stage3: o2n = [o2k|o1n]*[Vm|Vp] + b2n ; full = o2n + o2k ; soft-threshold
    floatx4 acc4[6];
#pragma unroll
    for (int j = 0; j < 6; j++) acc4[j] = z;
    bf16x8 a3[6];
#pragma unroll
    for (int k = 0; k < 6; k++) a3[k] = *(const bf16x8*)(Yw + lm * 200 + k * 32 + quad * 8);
#pragma unroll
    for (int k = 0; k < 6; k++)
#pragma unroll
        for (int j = 0; j < 6; j++) {
            bf16x8 w = *(const bf16x8*)(V2s + (size_t)(j * 16 + lm) * 192 + k * 32 + quad * 8);
            acc4[j] = __builtin_amdgcn_mfma_f32_16x16x32_bf16(a3[k], w, acc4[j], 0, 0, 0);
        }
#pragma unroll
    for (int j = 0; j < 6; j++) {
        int n = j * 16 + lm;
        float bB = b2l[768 + b * 96 + n];
#pragma unroll
        for (int r = 0; r < 4; r++) {
            int m = m0 + wave * 16 + quad * 4 + r;
            if (m >= NROW) continue;
            float full = acc4[j][r] + bB + o2k[j][r];
            float v = (full > LAMF) ? (full - LAMF) : ((full < -LAMF) ? (full + LAMF) : 0.f);
            ybuf16[(size_t)m * 768 + b * 96 + n] = f2b(v);
        }
    }
}

// ---------------- host ----------------
extern "C" void kernel_launch(void* const* d_in, const int* in_sizes, int n_in,
                              void* d_out, int out_size, void* d_ws, size_t ws_size,
                              hipStream_t stream) {
    const float* x       = (const float*)d_in[0];
    const float* patch_w = (const float*)d_in[1];
    const float* patch_b = (const float*)d_in[2];
    const float* pos     = (const float*)d_in[3];
    const float* n1w     = (const float*)d_in[4];
    const float* n1b     = (const float*)d_in[5];
    const float* w1      = (const float*)d_in[6];
    const float* b1      = (const float*)d_in[7];
    const float* w2      = (const float*)d_in[8];
    const float* b2      = (const float*)d_in[9];
    const float* n2w     = (const float*)d_in[10];
    const float* n2b     = (const float*)d_in[11];
    const float* fc1w    = (const float*)d_in[12];
    const float* fc1b    = (const float*)d_in[13];
    const float* fc2w    = (const float*)d_in[14];
    const float* fc2b    = (const float*)d_in[15];
    const float* headw   = (const float*)d_in[16];
    float* out = (float*)d_out;
    float* wsp = (float*)d_ws;

    size_t off = 0;
    auto af_ = [&](size_t n) { float* p = wsp + off; off += (n + 3) & ~(size_t)3; return p; };
    auto au_ = [&](size_t n) { u16* p = (u16*)(wsp + off); off += ((n + 1) / 2 + 3) & ~(size_t)3; return p; };

    u16* TCcs = au_(770 * 768);
    float* T_W1 = af_(90 * 192);
    float* T_H  = af_(90 * 96);
    float* T_W2 = af_(180 * 48);
    u16* WB1k = au_(147456);
    u16* WB1n = au_(147456);
    u16* WB2  = au_(147456);
    u16* WB2s = au_(147456);
    u16* fc1w16 = au_(2359296);
    u16* fc2w16 = au_(2359296);
    float* cur = af_(3110400);
    float* mid = af_(3110400);
    float* tlnA = af_(3110400);
    u16* tlnA16 = au_(3110400);
    u16* tlnB16 = au_(3110400);
    u16* Xb = au_(1589760);
    u16* ybuf16 = au_(794880);
    float* F3re = af_(1559250);
    float* F3im = af_(1559250);
    float* F4re = af_(1559250);
    float* F4im = af_(1559250);
    float* SCR = af_(10368000);  // holds patchA16 (20.74M u16) in patch phase
    // DFT scratch inside SCR
    float* D1 = SCR;                         // [192][LD1]   (90 xr + 90 xi + pad)
    float* D2 = D1 + (size_t)192 * LD1;      // [96][LD1]    (45 xr + 45 xi + pad)
    float* D3 = D2 + (size_t)96 * LD1;       // [48][LD1]    (23 xr + 23 xi + pad)
    float* D4 = D3 + (size_t)48 * LD1;       // [96][LD4]    (45 xr + 45 xi + pad)
    u16* hidden16 = (u16*)SCR;               // 12.44M u16 = 6.22M f (MLP phase)
    u16* patchA16 = (u16*)SCR;               // patch phase: gathered A [4050][5120] bf16
    u16* pw16 = fc1w16;                      // patch phase: patch weights (spans fc1w16+fc2w16)
    u16* Chi = (u16*)SCR;                    // head phase
    u16* Clo = Chi + 3110400;
    u16* Hhi = Clo + 3110400;
    u16* Hlo = Hhi + 3932160;
    size_t need = off * sizeof(float);
    if (ws_size < need) return;

    init_tables<<<2310, 256, 0, stream>>>(TCcs, T_W1, T_H, T_W2);

    // ---- patch embed: gather image -> bf16 A, then pipelined MFMA GEMM ----
    cast_f2b<<<3840, 256, 0, stream>>>(patch_w, pw16, 3932160);
    patch_gather<<<10125, 256, 0, stream>>>(x, patchA16);
    gemm_bf16<<<dim3(64, 6), 256, 0, stream>>>(patchA16, pw16, patch_b, pos, cur,
                                               NTOK, 768, 5120, 768, 2, 0, 0);

    for (int l = 0; l < 12; l++) {
        const float* w1l = w1 + (size_t)l * 147456;
        const float* b1l = b1 + (size_t)l * 1536;
        const float* w2l = w2 + (size_t)l * 147456;
        const float* b2l = b2 + (size_t)l * 1536;

        cast2_f2b<<<4608, 256, 0, stream>>>(fc1w + (size_t)l * 2359296,
                                            fc2w + (size_t)l * 2359296,
                                            fc1w16, fc2w16, 2359296);
        wpm_prep<<<576, 256, 0, stream>>>(w1l, w2l, WB1k, WB1n, WB2, WB2s);
        ln_kernel<<<NTOK, 256, 0, stream>>>(cur, n1w + l * 768, n1b + l * 768, tlnA, tlnA16);

        // DHT1: C-axis DFT (merged cos|sin) -> D1 [w][h][k] re plane + im plane
        gemm_bf16<<<dim3(64, 7), 256, 0, stream>>>(tlnA16, TCcs, nullptr, nullptr, D1,
                                                   NTOK, 770, 768, 90 * LD1, 3, 90, LD1);
        // W-axis (90 -> 45 selected) -> D2 [h][j][k]
        dft_gemm<<<dim3(2, 136), 256, 0, stream>>>(T_W1, D1, D2, D2 + (size_t)45 * LD1,
                                                   90, 17325, 192, LD1, 1, LD1);
        // H-axis (45 -> 45) -> F3 planes [i][j][k]
        dft_gemm<<<dim3(2, 136), 256, 0, stream>>>(T_H, D2, F3re, F3im,
                                                   90, 17325, 96, LD1, 0, 17325);
        build_an<<<(NROW * 768 + 255) / 256, 256, 0, stream>>>(F3re, F3im, tlnA, Xb);

        // fused block MLP
        blk_fused<<<dim3(8, 33), 128, 0, stream>>>(Xb, WB1k, WB1n, WB2, WB2s,
                                                   b1l, b2l, ybuf16);

        // DHT2: C-axis DFT (merged) -> D3 [w0][h][k] re + im planes
        gemm_bf16<<<dim3(17, 7), 256, 0, stream>>>(ybuf16, TCcs, nullptr, nullptr, D3,
                                                   NROW, 770, 768, 23 * LD1, 3, 23, LD1);
        // W-axis (23 -> 90) -> D4 [h][j][k]
        dft_gemm<<<dim3(3, 136), 256, 0, stream>>>(T_W2, D3, D4, D4 + (size_t)45 * LD4,
                                                   180, 17325, 48, LD1, 1, LD4);
        // H-axis (45 -> 45) -> F4 planes [i][j][k]
        dft_gemm<<<dim3(2, 271), 256, 0, stream>>>(T_H, D4, F4re, F4im,
                                                   90, 34650, 96, LD4, 0, 34650);
        // combine + LN2 fused
        ln2c_kernel<<<NTOK, 256, 0, stream>>>(F4re, F4im, cur, tlnA,
                                              n2w + l * 768, n2b + l * 768, mid, tlnB16);

        // MLP
        gemm_bf16<<<dim3(64, 24), 256, 0, stream>>>(tlnB16, fc1w16, fc1b + l * 3072, nullptr,
                                                    hidden16, NTOK, 3072, 768, 3072, 1, 0, 0);
        gemm_bf16<<<dim3(64, 6), 256, 0, stream>>>(hidden16, fc2w16, fc2b + l * 768, mid,
                                                   cur, NTOK, 768, 3072, 768, 2, 0, 0);
    }

    // ---- head: split-bf16 GEMM (permuted B rows) + coalesced scatter ----
    cast_split<<<3038, 256, 0, stream>>>(cur, Chi, Clo, 3110400);
    cast_split_perm<<<3840, 256, 0, stream>>>(headw, Hhi, Hlo);
    gemm_split<<<dim3(32, 40), 256, 0, stream>>>(Chi, Clo, Hhi, Hlo, out,
                                                 NTOK, 5120, 768);
}